// Round 1
// baseline (427.338 us; speedup 1.0000x reference)
//
#include <hip/hip_runtime.h>
#include <hip/hip_bf16.h>

// Problem constants (T=2048, B=32, N=1024, H=8, K=128, K2=16)
#define T_DIM 2048
#define B_DIM 32
#define N_DIM 1024
#define H_DIM 8
#define K_DIM 128
#define Q_DIM 16
#define M_ROWS (T_DIM * B_DIM)   // 65536 GEMM rows (t*32+b)

typedef __bf16 bf16x8 __attribute__((ext_vector_type(8)));
typedef __bf16 bf16x4 __attribute__((ext_vector_type(4)));
typedef float  f32x4  __attribute__((ext_vector_type(4)));

__device__ inline bf16x8 cvt8(float4 a, float4 b) {
    bf16x8 r;
    r[0] = (__bf16)a.x; r[1] = (__bf16)a.y; r[2] = (__bf16)a.z; r[3] = (__bf16)a.w;
    r[4] = (__bf16)b.x; r[5] = (__bf16)b.y; r[6] = (__bf16)b.z; r[7] = (__bf16)b.w;
    return r;
}

// ---------------------------------------------------------------------------
// K1: X = hyp(65536x1024) . Wmh^T(1024x1024) + bmh   -> bf16 X
// 128x128 tile, BK=32, 4 waves (2x2), each wave 64x64 = 4x4 frags of 16x16x32.
// A and B reg-staged from f32 with on-the-fly bf16 convert (no pre-convert pass).
// grid = (8 col-blocks fastest, 512 row-blocks) so the 8 sharers of an A-panel
// are dispatch-adjacent -> A-panel L2 reuse; B (4MB) is LLC-resident.
// ---------------------------------------------------------------------------
__global__ __launch_bounds__(256, 2)
void gemm_x_kernel(const float* __restrict__ A,    // hyp  (65536,1024)
                   const float* __restrict__ Bw,   // Wmh  (1024 out,1024 in)
                   const float* __restrict__ bias, // bmh flat (1024)
                   __bf16* __restrict__ X)
{
    __shared__ __bf16 As[128 * 32];
    __shared__ __bf16 Bs[128 * 32];

    const int tid  = threadIdx.x;
    const int lane = tid & 63;
    const int w    = tid >> 6;
    const int wr   = w >> 1;
    const int wc   = w & 1;
    const int bn   = blockIdx.x;            // 0..7
    const int bm   = blockIdx.y;            // 0..511
    const int row0 = bm * 128;
    const int col0 = bn * 128;

    const int srow = tid >> 2;               // 0..63
    const int sk8  = (tid & 3) * 8;          // 0,8,16,24

    f32x4 acc[4][4];
    #pragma unroll
    for (int i = 0; i < 4; ++i)
        #pragma unroll
        for (int j = 0; j < 4; ++j)
            acc[i][j] = f32x4{0.f, 0.f, 0.f, 0.f};

    const int fr = lane & 15;
    const int g8 = (lane >> 4) * 8;

    for (int kt = 0; kt < 32; ++kt) {
        const int k0 = kt * 32;
        // global f32 loads (regs) -- no LDS touched yet
        const float* ap0 = A  + (row0 + srow) * 1024 + k0 + sk8;
        const float* ap1 = A  + (row0 + 64 + srow) * 1024 + k0 + sk8;
        const float* bp0 = Bw + (col0 + srow) * 1024 + k0 + sk8;
        const float* bp1 = Bw + (col0 + 64 + srow) * 1024 + k0 + sk8;
        float4 a00 = *(const float4*)ap0;
        float4 a01 = *(const float4*)(ap0 + 4);
        float4 a10 = *(const float4*)ap1;
        float4 a11 = *(const float4*)(ap1 + 4);
        float4 b00 = *(const float4*)bp0;
        float4 b01 = *(const float4*)(bp0 + 4);
        float4 b10 = *(const float4*)bp1;
        float4 b11 = *(const float4*)(bp1 + 4);

        __syncthreads();   // previous iteration's LDS readers done
        *(bf16x8*)(As + srow * 32 + sk8)        = cvt8(a00, a01);
        *(bf16x8*)(As + (64 + srow) * 32 + sk8) = cvt8(a10, a11);
        *(bf16x8*)(Bs + srow * 32 + sk8)        = cvt8(b00, b01);
        *(bf16x8*)(Bs + (64 + srow) * 32 + sk8) = cvt8(b10, b11);
        __syncthreads();   // staging visible

        bf16x8 af[4], bf[4];
        #pragma unroll
        for (int m = 0; m < 4; ++m)
            af[m] = *(const bf16x8*)(As + (wr * 64 + m * 16 + fr) * 32 + g8);
        #pragma unroll
        for (int n = 0; n < 4; ++n)
            bf[n] = *(const bf16x8*)(Bs + (wc * 64 + n * 16 + fr) * 32 + g8);

        #pragma unroll
        for (int m = 0; m < 4; ++m)
            #pragma unroll
            for (int n = 0; n < 4; ++n)
                acc[m][n] = __builtin_amdgcn_mfma_f32_16x16x32_bf16(af[m], bf[n], acc[m][n], 0, 0, 0);
    }

    // epilogue: + bias(col), store bf16. C/D layout: col=lane&15, row=(lane>>4)*4+reg
    const int g4 = lane >> 4;
    #pragma unroll
    for (int n = 0; n < 4; ++n) {
        const int col = col0 + wc * 64 + n * 16 + fr;
        const float bv = bias[col];
        #pragma unroll
        for (int m = 0; m < 4; ++m) {
            #pragma unroll
            for (int r = 0; r < 4; ++r) {
                const int row = row0 + wr * 64 + m * 16 + g4 * 4 + r;
                X[(long)row * 1024 + col] = (__bf16)(acc[m][n][r] + bv);
            }
        }
    }
}

// ---------------------------------------------------------------------------
// K2: partial sums over t for the time-mean. block = (tc, b), 1024 blocks.
// Each block sums 64 t's over all 1024 columns (thread = 4 cols, 8B loads).
// ---------------------------------------------------------------------------
__global__ __launch_bounds__(256)
void mean_part_k(const __bf16* __restrict__ X, float* __restrict__ mpart)
{
    const int bx = blockIdx.x;
    const int b  = bx & 31;
    const int tc = bx >> 5;          // 0..31
    const int j4 = threadIdx.x * 4;
    float a0 = 0.f, a1 = 0.f, a2 = 0.f, a3 = 0.f;
    #pragma unroll 4
    for (int i = 0; i < 64; ++i) {
        const int t = tc * 64 + i;
        bf16x4 v = *(const bf16x4*)(X + (long)(t * 32 + b) * 1024 + j4);
        a0 += (float)v[0]; a1 += (float)v[1]; a2 += (float)v[2]; a3 += (float)v[3];
    }
    float4* mp = (float4*)(mpart + ((long)tc * 32 + b) * 1024 + j4);
    *mp = make_float4(a0, a1, a2, a3);
}

// ---------------------------------------------------------------------------
// K3: finalize mean, compute gate2[b,h,q] = tanh(m . Wm[q] + bWm[q]). 32 blocks.
// ---------------------------------------------------------------------------
__global__ __launch_bounds__(256)
void gate2_k(const float* __restrict__ mpart, const float* __restrict__ Wm,
             const float* __restrict__ bWm, float* __restrict__ g2)
{
    __shared__ float mrow[1024];
    const int b = blockIdx.x;
    for (int j = threadIdx.x; j < 1024; j += 256) {
        float s = 0.f;
        #pragma unroll 8
        for (int tc = 0; tc < 32; ++tc) s += mpart[((long)tc * 32 + b) * 1024 + j];
        mrow[j] = s * (1.0f / 2048.0f);
    }
    __syncthreads();
    if (threadIdx.x < 128) {
        const int h = threadIdx.x >> 4;
        const int q = threadIdx.x & 15;
        float d = bWm[q];
        #pragma unroll 8
        for (int k = 0; k < 128; ++k) d += mrow[h * 128 + k] * Wm[q * 128 + k];
        g2[(b * 8 + h) * 16 + q] = tanhf(d);
    }
}

// ---------------------------------------------------------------------------
// K4: scores. X viewed as (524288 rows = bt*8+h, 128). One wave = 16 rows.
// G = X . W^T via 4x mfma_16x16x32; epilogue tanh(+bW)*g2*Wh, 16-lane reduce,
// s[b,h,t] = sum + bWh.  8192 blocks x 4 waves.
// ---------------------------------------------------------------------------
__global__ __launch_bounds__(256)
void scores_k(const __bf16* __restrict__ X, const float* __restrict__ W,
              const float* __restrict__ bW, const float* __restrict__ g2,
              const float* __restrict__ Wh, const float* __restrict__ bWh,
              float* __restrict__ sbuf)
{
    const int tid   = threadIdx.x;
    const int lane  = tid & 63;
    const int w     = tid >> 6;
    const int gw    = blockIdx.x * 4 + w;
    const int rbase = gw * 16;
    const int q     = lane & 15;
    const int g4    = lane >> 4;

    // B frags from W (f32 -> bf16): B[k][q] = W[q][k]
    bf16x8 bfr[4];
    #pragma unroll
    for (int c = 0; c < 4; ++c) {
        const float* wp = W + q * 128 + c * 32 + g4 * 8;
        float4 w0 = *(const float4*)wp;
        float4 w1 = *(const float4*)(wp + 4);
        bfr[c] = cvt8(w0, w1);
    }
    // A frags straight from global bf16 X (per-row 64B chunks, L2-friendly)
    const __bf16* xp = X + (long)(rbase + q) * 128 + g4 * 8;
    bf16x8 afr[4];
    #pragma unroll
    for (int c = 0; c < 4; ++c) afr[c] = *(const bf16x8*)(xp + c * 32);

    f32x4 acc = f32x4{0.f, 0.f, 0.f, 0.f};
    #pragma unroll
    for (int c = 0; c < 4; ++c)
        acc = __builtin_amdgcn_mfma_f32_16x16x32_bf16(afr[c], bfr[c], acc, 0, 0, 0);

    const float whq  = Wh[q];
    const float bWv  = bW[q];
    const float bWhv = *bWh;
    #pragma unroll
    for (int r = 0; r < 4; ++r) {
        const int row = rbase + g4 * 4 + r;   // = bt*8 + h
        const int h   = row & 7;
        const int bt  = row >> 3;
        const int b   = bt & 31;
        const int t   = bt >> 5;
        float val = tanhf(acc[r] + bWv) * g2[(b * 8 + h) * 16 + q] * whq;
        val += __shfl_xor(val, 1);
        val += __shfl_xor(val, 2);
        val += __shfl_xor(val, 4);
        val += __shfl_xor(val, 8);
        if (q == 0) sbuf[(b * 8 + h) * 2048 + t] = val + bWhv;
    }
}

// ---------------------------------------------------------------------------
// K5: softmax over t, in place. 256 blocks (b*8+h), 256 threads x 8 vals.
// ---------------------------------------------------------------------------
__global__ __launch_bounds__(256)
void softmax_k(float* __restrict__ s)
{
    __shared__ float red[256];
    const int bh = blockIdx.x;
    const int tid = threadIdx.x;
    float* row = s + bh * 2048;
    float4 v0 = *(const float4*)(row + tid * 8);
    float4 v1 = *(const float4*)(row + tid * 8 + 4);
    float v[8] = {v0.x, v0.y, v0.z, v0.w, v1.x, v1.y, v1.z, v1.w};
    float mx = v[0];
    #pragma unroll
    for (int i = 1; i < 8; ++i) mx = fmaxf(mx, v[i]);
    red[tid] = mx;
    __syncthreads();
    for (int st = 128; st > 0; st >>= 1) {
        if (tid < st) red[tid] = fmaxf(red[tid], red[tid + st]);
        __syncthreads();
    }
    mx = red[0];
    __syncthreads();
    float sum = 0.f;
    #pragma unroll
    for (int i = 0; i < 8; ++i) { v[i] = expf(v[i] - mx); sum += v[i]; }
    red[tid] = sum;
    __syncthreads();
    for (int st = 128; st > 0; st >>= 1) {
        if (tid < st) red[tid] += red[tid + st];
        __syncthreads();
    }
    const float inv = 1.0f / red[0];
    *(float4*)(row + tid * 8)     = make_float4(v[0] * inv, v[1] * inv, v[2] * inv, v[3] * inv);
    *(float4*)(row + tid * 8 + 4) = make_float4(v[4] * inv, v[5] * inv, v[6] * inv, v[7] * inv);
}

// ---------------------------------------------------------------------------
// K6: weighted sum over t, t split 8 ways for occupancy. 2048 blocks.
// thread = (tr 0..7, kq 0..31) -> 4 k's via 8B bf16x4 loads.
// ---------------------------------------------------------------------------
__global__ __launch_bounds__(256)
void wsum_k(const float* __restrict__ a, const __bf16* __restrict__ X,
            float* __restrict__ wpart)
{
    __shared__ float pk[8 * 128];
    const int bx = blockIdx.x;
    const int tc = bx & 7;
    const int bh = bx >> 3;
    const int b  = bh >> 3;
    const int h  = bh & 7;
    const int tid = threadIdx.x;
    const int kq = tid & 31;
    const int tr = tid >> 5;
    const float* ar = a + bh * 2048 + tc * 256;
    float a0 = 0.f, a1 = 0.f, a2 = 0.f, a3 = 0.f;
    #pragma unroll 4
    for (int i = tr; i < 256; i += 8) {
        const int t = tc * 256 + i;
        const float av = ar[i];
        bf16x4 xv = *(const bf16x4*)(X + (long)(t * 32 + b) * 1024 + h * 128 + kq * 4);
        a0 += av * (float)xv[0];
        a1 += av * (float)xv[1];
        a2 += av * (float)xv[2];
        a3 += av * (float)xv[3];
    }
    pk[tr * 128 + kq * 4 + 0] = a0;
    pk[tr * 128 + kq * 4 + 1] = a1;
    pk[tr * 128 + kq * 4 + 2] = a2;
    pk[tr * 128 + kq * 4 + 3] = a3;
    __syncthreads();
    if (tid < 128) {
        float s2 = 0.f;
        #pragma unroll
        for (int r = 0; r < 8; ++r) s2 += pk[r * 128 + tid];
        wpart[(long)bx * 128 + tid] = s2;
    }
}

// K7: reduce the 8 t-chunks. 128 blocks x 256 threads = 32768 outputs.
__global__ __launch_bounds__(256)
void wsum_fin(const float* __restrict__ wpart, float* __restrict__ out)
{
    const int idx = blockIdx.x * 256 + threadIdx.x;
    const int k  = idx & 127;
    const int bh = idx >> 7;
    const int b  = bh >> 3;
    const int h  = bh & 7;
    float s = 0.f;
    #pragma unroll
    for (int tc = 0; tc < 8; ++tc) s += wpart[(bh * 8 + tc) * 128 + k];
    out[b * 1024 + h * 128 + k] = s;
}

extern "C" void kernel_launch(void* const* d_in, const int* in_sizes, int n_in,
                              void* d_out, int out_size, void* d_ws, size_t ws_size,
                              hipStream_t stream)
{
    const float* hyp = (const float*)d_in[0];
    const float* Wmh = (const float*)d_in[1];
    const float* bmh = (const float*)d_in[2];
    const float* W   = (const float*)d_in[3];
    const float* bW  = (const float*)d_in[4];
    const float* Wm  = (const float*)d_in[5];
    const float* bWm = (const float*)d_in[6];
    const float* Wh  = (const float*)d_in[7];
    const float* bWh = (const float*)d_in[8];
    float* out = (float*)d_out;

    // workspace layout (~135 MB)
    char* ws = (char*)d_ws;
    __bf16* X    = (__bf16*)(ws);                                   // 134217728 B
    float*  mpart = (float*)(ws + 134217728);                       //   4194304 B
    float*  g2    = (float*)(ws + 134217728 + 4194304);             //     16384 B
    float*  sbuf  = (float*)(ws + 134217728 + 4194304 + 16384);     //   2097152 B
    float*  wpart = (float*)(ws + 134217728 + 4194304 + 16384 + 2097152); // 1048576 B

    gemm_x_kernel<<<dim3(8, 512), 256, 0, stream>>>(hyp, Wmh, bmh, X);
    mean_part_k<<<1024, 256, 0, stream>>>(X, mpart);
    gate2_k<<<32, 256, 0, stream>>>(mpart, Wm, bWm, g2);
    scores_k<<<8192, 256, 0, stream>>>(X, W, bW, g2, Wh, bWh, sbuf);
    softmax_k<<<256, 256, 0, stream>>>(sbuf);
    wsum_k<<<2048, 256, 0, stream>>>(sbuf, X, wpart);
    wsum_fin<<<128, 256, 0, stream>>>(wpart, out);
}

// Round 2
// 420.050 us; speedup vs baseline: 1.0174x; 1.0174x over previous
//
#include <hip/hip_runtime.h>
#include <hip/hip_bf16.h>

// Problem constants (T=2048, B=32, N=1024, H=8, K=128, K2=16)
#define T_DIM 2048
#define B_DIM 32
#define N_DIM 1024
#define H_DIM 8
#define K_DIM 128
#define Q_DIM 16

typedef __bf16 bf16x8 __attribute__((ext_vector_type(8)));
typedef __bf16 bf16x4 __attribute__((ext_vector_type(4)));
typedef float  f32x4  __attribute__((ext_vector_type(4)));

__device__ inline bf16x8 cvt8(float4 a, float4 b) {
    bf16x8 r;
    r[0] = (__bf16)a.x; r[1] = (__bf16)a.y; r[2] = (__bf16)a.z; r[3] = (__bf16)a.w;
    r[4] = (__bf16)b.x; r[5] = (__bf16)b.y; r[6] = (__bf16)b.z; r[7] = (__bf16)b.w;
    return r;
}

// ---------------------------------------------------------------------------
// K0: f32 -> bf16 convert, 8 elems/thread, fully vectorized.
// ---------------------------------------------------------------------------
__global__ __launch_bounds__(256)
void cvt_f32_bf16(const float* __restrict__ s, __bf16* __restrict__ d)
{
    const long i = ((long)blockIdx.x * 256 + threadIdx.x) * 8;
    float4 a = *(const float4*)(s + i);
    float4 b = *(const float4*)(s + i + 4);
    *(bf16x8*)(d + i) = cvt8(a, b);
}

// ---------------------------------------------------------------------------
// K1 (fast): X = Ab(65536x1024 bf16) . Bb^T(1024x1024 bf16) + bias -> bf16 X
// m97 structure: 128x128 tile, BK=64, 4 waves (2x2), global_load_lds width=16,
// linear LDS, 2 barriers per K-step. 1D grid + bijective XCD swizzle,
// row-major logical order (8 col-blocks of one row-panel share an XCD L2).
// ---------------------------------------------------------------------------
__global__ __launch_bounds__(256)
void gemm_x_fast(const __bf16* __restrict__ A, const __bf16* __restrict__ Bw,
                 const float* __restrict__ bias, __bf16* __restrict__ X)
{
    __shared__ __bf16 As[128 * 64];   // [row][k], row stride 64 elems
    __shared__ __bf16 Bs[128 * 64];

    const int tid  = threadIdx.x;
    const int lane = tid & 63;
    const int w    = tid >> 6;        // wave 0..3
    const int wr   = w >> 1;
    const int wc   = w & 1;

    const int bid  = blockIdx.x;                  // 4096 blocks, 4096%8==0
    const int wgid = (bid & 7) * 512 + (bid >> 3); // XCD k -> logical [k*512,+512)
    const int bm   = wgid >> 3;                   // 0..511 row-panel
    const int bn   = wgid & 7;                    // 0..7  col-panel
    const long row0 = (long)bm * 128;
    const long col0 = (long)bn * 128;

    // staging: wave w fills LDS rows [w*32, w*32+32), chunk c covers 8 rows.
    const int ldr = w * 32 + (lane >> 3);   // tile row for chunk c=0 (+8c)
    const int ldk = (lane & 7) * 8;         // k elem offset (16B granules)
    const __bf16* Abase = A  + (row0 + ldr) * 1024 + ldk;
    const __bf16* Bbase = Bw + (col0 + ldr) * 1024 + ldk;

    f32x4 acc[4][4];
    #pragma unroll
    for (int i = 0; i < 4; ++i)
        #pragma unroll
        for (int j = 0; j < 4; ++j)
            acc[i][j] = f32x4{0.f, 0.f, 0.f, 0.f};

    const int fr = lane & 15;
    const int g8 = (lane >> 4) * 8;

    for (int kt = 0; kt < 16; ++kt) {
        const int k0 = kt * 64;
        #pragma unroll
        for (int c = 0; c < 4; ++c) {
            __builtin_amdgcn_global_load_lds(
                (const __attribute__((address_space(1))) void*)(Abase + (long)c * 8192 + k0),
                (__attribute__((address_space(3))) void*)(As + w * 2048 + c * 512),
                16, 0, 0);
            __builtin_amdgcn_global_load_lds(
                (const __attribute__((address_space(1))) void*)(Bbase + (long)c * 8192 + k0),
                (__attribute__((address_space(3))) void*)(Bs + w * 2048 + c * 512),
                16, 0, 0);
        }
        __syncthreads();   // drains vmcnt(0): staged tile visible

        bf16x8 af[2][4], bf[2][4];
        #pragma unroll
        for (int h = 0; h < 2; ++h) {
            #pragma unroll
            for (int m = 0; m < 4; ++m)
                af[h][m] = *(const bf16x8*)(As + (wr * 64 + m * 16 + fr) * 64 + h * 32 + g8);
            #pragma unroll
            for (int n = 0; n < 4; ++n)
                bf[h][n] = *(const bf16x8*)(Bs + (wc * 64 + n * 16 + fr) * 64 + h * 32 + g8);
        }
        #pragma unroll
        for (int h = 0; h < 2; ++h)
            #pragma unroll
            for (int m = 0; m < 4; ++m)
                #pragma unroll
                for (int n = 0; n < 4; ++n)
                    acc[m][n] = __builtin_amdgcn_mfma_f32_16x16x32_bf16(af[h][m], bf[h][n], acc[m][n], 0, 0, 0);
        __syncthreads();   // readers done before next overwrite
    }

    // epilogue: + bias(col), store bf16. C/D: col=lane&15, row=(lane>>4)*4+r
    const int g4 = lane >> 4;
    #pragma unroll
    for (int n = 0; n < 4; ++n) {
        const long col = col0 + wc * 64 + n * 16 + fr;
        const float bv = bias[col];
        #pragma unroll
        for (int m = 0; m < 4; ++m) {
            #pragma unroll
            for (int r = 0; r < 4; ++r) {
                const long row = row0 + wr * 64 + m * 16 + g4 * 4 + r;
                X[row * 1024 + col] = (__bf16)(acc[m][n][r] + bv);
            }
        }
    }
}

// ---------------------------------------------------------------------------
// K1 (fallback, round-1): reg-staged f32 GEMM, used only if ws too small.
// ---------------------------------------------------------------------------
__global__ __launch_bounds__(256, 2)
void gemm_x_kernel(const float* __restrict__ A, const float* __restrict__ Bw,
                   const float* __restrict__ bias, __bf16* __restrict__ X)
{
    __shared__ __bf16 As[128 * 32];
    __shared__ __bf16 Bs[128 * 32];
    const int tid  = threadIdx.x;
    const int lane = tid & 63;
    const int w    = tid >> 6;
    const int wr   = w >> 1;
    const int wc   = w & 1;
    const int bn   = blockIdx.x;
    const int bm   = blockIdx.y;
    const int row0 = bm * 128;
    const int col0 = bn * 128;
    const int srow = tid >> 2;
    const int sk8  = (tid & 3) * 8;
    f32x4 acc[4][4];
    #pragma unroll
    for (int i = 0; i < 4; ++i)
        #pragma unroll
        for (int j = 0; j < 4; ++j)
            acc[i][j] = f32x4{0.f, 0.f, 0.f, 0.f};
    const int fr = lane & 15;
    const int g8 = (lane >> 4) * 8;
    for (int kt = 0; kt < 32; ++kt) {
        const int k0 = kt * 32;
        const float* ap0 = A  + (row0 + srow) * 1024 + k0 + sk8;
        const float* ap1 = A  + (row0 + 64 + srow) * 1024 + k0 + sk8;
        const float* bp0 = Bw + (col0 + srow) * 1024 + k0 + sk8;
        const float* bp1 = Bw + (col0 + 64 + srow) * 1024 + k0 + sk8;
        float4 a00 = *(const float4*)ap0;
        float4 a01 = *(const float4*)(ap0 + 4);
        float4 a10 = *(const float4*)ap1;
        float4 a11 = *(const float4*)(ap1 + 4);
        float4 b00 = *(const float4*)bp0;
        float4 b01 = *(const float4*)(bp0 + 4);
        float4 b10 = *(const float4*)bp1;
        float4 b11 = *(const float4*)(bp1 + 4);
        __syncthreads();
        *(bf16x8*)(As + srow * 32 + sk8)        = cvt8(a00, a01);
        *(bf16x8*)(As + (64 + srow) * 32 + sk8) = cvt8(a10, a11);
        *(bf16x8*)(Bs + srow * 32 + sk8)        = cvt8(b00, b01);
        *(bf16x8*)(Bs + (64 + srow) * 32 + sk8) = cvt8(b10, b11);
        __syncthreads();
        bf16x8 af[4], bf[4];
        #pragma unroll
        for (int m = 0; m < 4; ++m)
            af[m] = *(const bf16x8*)(As + (wr * 64 + m * 16 + fr) * 32 + g8);
        #pragma unroll
        for (int n = 0; n < 4; ++n)
            bf[n] = *(const bf16x8*)(Bs + (wc * 64 + n * 16 + fr) * 32 + g8);
        #pragma unroll
        for (int m = 0; m < 4; ++m)
            #pragma unroll
            for (int n = 0; n < 4; ++n)
                acc[m][n] = __builtin_amdgcn_mfma_f32_16x16x32_bf16(af[m], bf[n], acc[m][n], 0, 0, 0);
    }
    const int g4 = lane >> 4;
    #pragma unroll
    for (int n = 0; n < 4; ++n) {
        const int col = col0 + wc * 64 + n * 16 + fr;
        const float bv = bias[col];
        #pragma unroll
        for (int m = 0; m < 4; ++m) {
            #pragma unroll
            for (int r = 0; r < 4; ++r) {
                const int row = row0 + wr * 64 + m * 16 + g4 * 4 + r;
                X[(long)row * 1024 + col] = (__bf16)(acc[m][n][r] + bv);
            }
        }
    }
}

// ---------------------------------------------------------------------------
// K2: partial sums over t for the time-mean. block = (tc, b), 1024 blocks.
// ---------------------------------------------------------------------------
__global__ __launch_bounds__(256)
void mean_part_k(const __bf16* __restrict__ X, float* __restrict__ mpart)
{
    const int bx = blockIdx.x;
    const int b  = bx & 31;
    const int tc = bx >> 5;
    const int j4 = threadIdx.x * 4;
    float a0 = 0.f, a1 = 0.f, a2 = 0.f, a3 = 0.f;
    #pragma unroll 4
    for (int i = 0; i < 64; ++i) {
        const int t = tc * 64 + i;
        bf16x4 v = *(const bf16x4*)(X + (long)(t * 32 + b) * 1024 + j4);
        a0 += (float)v[0]; a1 += (float)v[1]; a2 += (float)v[2]; a3 += (float)v[3];
    }
    float4* mp = (float4*)(mpart + ((long)tc * 32 + b) * 1024 + j4);
    *mp = make_float4(a0, a1, a2, a3);
}

// ---------------------------------------------------------------------------
// K3: finalize mean, gate2[b,h,q] = tanh(m . Wm[q] + bWm[q]). 32 blocks.
// ---------------------------------------------------------------------------
__global__ __launch_bounds__(256)
void gate2_k(const float* __restrict__ mpart, const float* __restrict__ Wm,
             const float* __restrict__ bWm, float* __restrict__ g2)
{
    __shared__ float mrow[1024];
    const int b = blockIdx.x;
    for (int j = threadIdx.x; j < 1024; j += 256) {
        float s = 0.f;
        #pragma unroll 8
        for (int tc = 0; tc < 32; ++tc) s += mpart[((long)tc * 32 + b) * 1024 + j];
        mrow[j] = s * (1.0f / 2048.0f);
    }
    __syncthreads();
    if (threadIdx.x < 128) {
        const int h = threadIdx.x >> 4;
        const int q = threadIdx.x & 15;
        float d = bWm[q];
        #pragma unroll 8
        for (int k = 0; k < 128; ++k) d += mrow[h * 128 + k] * Wm[q * 128 + k];
        g2[(b * 8 + h) * 16 + q] = tanhf(d);
    }
}

// ---------------------------------------------------------------------------
// K4: scores. X viewed as (524288 rows = bt*8+h, 128). One wave = 16 rows.
// ---------------------------------------------------------------------------
__global__ __launch_bounds__(256)
void scores_k(const __bf16* __restrict__ X, const float* __restrict__ W,
              const float* __restrict__ bW, const float* __restrict__ g2,
              const float* __restrict__ Wh, const float* __restrict__ bWh,
              float* __restrict__ sbuf)
{
    const int tid   = threadIdx.x;
    const int lane  = tid & 63;
    const int w     = tid >> 6;
    const int gw    = blockIdx.x * 4 + w;
    const int rbase = gw * 16;
    const int q     = lane & 15;
    const int g4    = lane >> 4;

    bf16x8 bfr[4];
    #pragma unroll
    for (int c = 0; c < 4; ++c) {
        const float* wp = W + q * 128 + c * 32 + g4 * 8;
        float4 w0 = *(const float4*)wp;
        float4 w1 = *(const float4*)(wp + 4);
        bfr[c] = cvt8(w0, w1);
    }
    const __bf16* xp = X + (long)(rbase + q) * 128 + g4 * 8;
    bf16x8 afr[4];
    #pragma unroll
    for (int c = 0; c < 4; ++c) afr[c] = *(const bf16x8*)(xp + c * 32);

    f32x4 acc = f32x4{0.f, 0.f, 0.f, 0.f};
    #pragma unroll
    for (int c = 0; c < 4; ++c)
        acc = __builtin_amdgcn_mfma_f32_16x16x32_bf16(afr[c], bfr[c], acc, 0, 0, 0);

    const float whq  = Wh[q];
    const float bWv  = bW[q];
    const float bWhv = *bWh;
    #pragma unroll
    for (int r = 0; r < 4; ++r) {
        const int row = rbase + g4 * 4 + r;
        const int h   = row & 7;
        const int bt  = row >> 3;
        const int b   = bt & 31;
        const int t   = bt >> 5;
        float val = tanhf(acc[r] + bWv) * g2[(b * 8 + h) * 16 + q] * whq;
        val += __shfl_xor(val, 1);
        val += __shfl_xor(val, 2);
        val += __shfl_xor(val, 4);
        val += __shfl_xor(val, 8);
        if (q == 0) sbuf[(b * 8 + h) * 2048 + t] = val + bWhv;
    }
}

// ---------------------------------------------------------------------------
// K5: softmax over t, in place. 256 blocks (b*8+h).
// ---------------------------------------------------------------------------
__global__ __launch_bounds__(256)
void softmax_k(float* __restrict__ s)
{
    __shared__ float red[256];
    const int bh = blockIdx.x;
    const int tid = threadIdx.x;
    float* row = s + bh * 2048;
    float4 v0 = *(const float4*)(row + tid * 8);
    float4 v1 = *(const float4*)(row + tid * 8 + 4);
    float v[8] = {v0.x, v0.y, v0.z, v0.w, v1.x, v1.y, v1.z, v1.w};
    float mx = v[0];
    #pragma unroll
    for (int i = 1; i < 8; ++i) mx = fmaxf(mx, v[i]);
    red[tid] = mx;
    __syncthreads();
    for (int st = 128; st > 0; st >>= 1) {
        if (tid < st) red[tid] = fmaxf(red[tid], red[tid + st]);
        __syncthreads();
    }
    mx = red[0];
    __syncthreads();
    float sum = 0.f;
    #pragma unroll
    for (int i = 0; i < 8; ++i) { v[i] = expf(v[i] - mx); sum += v[i]; }
    red[tid] = sum;
    __syncthreads();
    for (int st = 128; st > 0; st >>= 1) {
        if (tid < st) red[tid] += red[tid + st];
        __syncthreads();
    }
    const float inv = 1.0f / red[0];
    *(float4*)(row + tid * 8)     = make_float4(v[0] * inv, v[1] * inv, v[2] * inv, v[3] * inv);
    *(float4*)(row + tid * 8 + 4) = make_float4(v[4] * inv, v[5] * inv, v[6] * inv, v[7] * inv);
}

// ---------------------------------------------------------------------------
// K6: weighted sum over t, t split 8 ways. 2048 blocks.
// ---------------------------------------------------------------------------
__global__ __launch_bounds__(256)
void wsum_k(const float* __restrict__ a, const __bf16* __restrict__ X,
            float* __restrict__ wpart)
{
    __shared__ float pk[8 * 128];
    const int bx = blockIdx.x;
    const int tc = bx & 7;
    const int bh = bx >> 3;
    const int b  = bh >> 3;
    const int h  = bh & 7;
    const int tid = threadIdx.x;
    const int kq = tid & 31;
    const int tr = tid >> 5;
    const float* ar = a + bh * 2048 + tc * 256;
    float a0 = 0.f, a1 = 0.f, a2 = 0.f, a3 = 0.f;
    #pragma unroll 4
    for (int i = tr; i < 256; i += 8) {
        const int t = tc * 256 + i;
        const float av = ar[i];
        bf16x4 xv = *(const bf16x4*)(X + (long)(t * 32 + b) * 1024 + h * 128 + kq * 4);
        a0 += av * (float)xv[0];
        a1 += av * (float)xv[1];
        a2 += av * (float)xv[2];
        a3 += av * (float)xv[3];
    }
    pk[tr * 128 + kq * 4 + 0] = a0;
    pk[tr * 128 + kq * 4 + 1] = a1;
    pk[tr * 128 + kq * 4 + 2] = a2;
    pk[tr * 128 + kq * 4 + 3] = a3;
    __syncthreads();
    if (tid < 128) {
        float s2 = 0.f;
        #pragma unroll
        for (int r = 0; r < 8; ++r) s2 += pk[r * 128 + tid];
        wpart[(long)bx * 128 + tid] = s2;
    }
}

// K7: reduce the 8 t-chunks.
__global__ __launch_bounds__(256)
void wsum_fin(const float* __restrict__ wpart, float* __restrict__ out)
{
    const int idx = blockIdx.x * 256 + threadIdx.x;
    const int k  = idx & 127;
    const int bh = idx >> 7;
    const int b  = bh >> 3;
    const int h  = bh & 7;
    float s = 0.f;
    #pragma unroll
    for (int tc = 0; tc < 8; ++tc) s += wpart[(bh * 8 + tc) * 128 + k];
    out[b * 1024 + h * 128 + k] = s;
}

extern "C" void kernel_launch(void* const* d_in, const int* in_sizes, int n_in,
                              void* d_out, int out_size, void* d_ws, size_t ws_size,
                              hipStream_t stream)
{
    const float* hyp = (const float*)d_in[0];
    const float* Wmh = (const float*)d_in[1];
    const float* bmh = (const float*)d_in[2];
    const float* W   = (const float*)d_in[3];
    const float* bW  = (const float*)d_in[4];
    const float* Wm  = (const float*)d_in[5];
    const float* bWm = (const float*)d_in[6];
    const float* Wh  = (const float*)d_in[7];
    const float* bWh = (const float*)d_in[8];
    float* out = (float*)d_out;

    char* ws = (char*)d_ws;
    const size_t SZ_X   = 134217728;   // 65536*1024*2
    const size_t SZ_AB  = 134217728;   // bf16 hyp
    const size_t SZ_BB  = 2097152;     // bf16 Wmh
    const size_t SZ_MP  = 4194304;
    const size_t SZ_G2  = 16384;
    const size_t SZ_SB  = 2097152;
    const size_t SZ_WP  = 1048576;
    const size_t need_fast = SZ_X + SZ_AB + SZ_BB + SZ_MP + SZ_G2 + SZ_SB + SZ_WP;

    __bf16* X;
    float *mpart, *g2, *sbuf, *wpart;

    if (ws_size >= need_fast) {
        X              = (__bf16*)(ws);
        __bf16* Ab     = (__bf16*)(ws + SZ_X);
        __bf16* Bb     = (__bf16*)(ws + SZ_X + SZ_AB);
        mpart = (float*)(ws + SZ_X + SZ_AB + SZ_BB);
        g2    = (float*)(ws + SZ_X + SZ_AB + SZ_BB + SZ_MP);
        sbuf  = (float*)(ws + SZ_X + SZ_AB + SZ_BB + SZ_MP + SZ_G2);
        wpart = (float*)(ws + SZ_X + SZ_AB + SZ_BB + SZ_MP + SZ_G2 + SZ_SB);

        cvt_f32_bf16<<<32768, 256, 0, stream>>>(hyp, Ab);   // 67108864 elems
        cvt_f32_bf16<<<512,   256, 0, stream>>>(Wmh, Bb);   // 1048576 elems
        gemm_x_fast<<<4096, 256, 0, stream>>>(Ab, Bb, bmh, X);
    } else {
        X     = (__bf16*)(ws);
        mpart = (float*)(ws + SZ_X);
        g2    = (float*)(ws + SZ_X + SZ_MP);
        sbuf  = (float*)(ws + SZ_X + SZ_MP + SZ_G2);
        wpart = (float*)(ws + SZ_X + SZ_MP + SZ_G2 + SZ_SB);
        gemm_x_kernel<<<dim3(8, 512), 256, 0, stream>>>(hyp, Wmh, bmh, X);
    }

    mean_part_k<<<1024, 256, 0, stream>>>(X, mpart);
    gate2_k<<<32, 256, 0, stream>>>(mpart, Wm, bWm, g2);
    scores_k<<<8192, 256, 0, stream>>>(X, W, bW, g2, Wh, bWh, sbuf);
    softmax_k<<<256, 256, 0, stream>>>(sbuf);
    wsum_k<<<2048, 256, 0, stream>>>(sbuf, X, wpart);
    wsum_fin<<<128, 256, 0, stream>>>(wpart, out);
}

// Round 3
// 361.180 us; speedup vs baseline: 1.1832x; 1.1630x over previous
//
#include <hip/hip_runtime.h>
#include <hip/hip_bf16.h>

// Problem constants (T=2048, B=32, N=1024, H=8, K=128, K2=16)
#define T_DIM 2048
#define B_DIM 32
#define N_DIM 1024
#define H_DIM 8
#define K_DIM 128
#define Q_DIM 16

typedef __bf16 bf16x8 __attribute__((ext_vector_type(8)));
typedef __bf16 bf16x4 __attribute__((ext_vector_type(4)));
typedef float  f32x4  __attribute__((ext_vector_type(4)));

__device__ inline bf16x8 cvt8(float4 a, float4 b) {
    bf16x8 r;
    r[0] = (__bf16)a.x; r[1] = (__bf16)a.y; r[2] = (__bf16)a.z; r[3] = (__bf16)a.w;
    r[4] = (__bf16)b.x; r[5] = (__bf16)b.y; r[6] = (__bf16)b.z; r[7] = (__bf16)b.w;
    return r;
}

// ---------------------------------------------------------------------------
// K0: f32 -> bf16 convert, 8 elems/thread.
// ---------------------------------------------------------------------------
__global__ __launch_bounds__(256)
void cvt_f32_bf16(const float* __restrict__ s, __bf16* __restrict__ d)
{
    const long i = ((long)blockIdx.x * 256 + threadIdx.x) * 8;
    float4 a = *(const float4*)(s + i);
    float4 b = *(const float4*)(s + i + 4);
    *(bf16x8*)(d + i) = cvt8(a, b);
}

// ---------------------------------------------------------------------------
// K1: 256x256-tile 8-phase GEMM (m201 template, plain HIP).
// X = Ab(65536x1024) . Bb^T(1024x1024) + bias -> bf16.
// 8 waves (2M x 4N), BK=64, LDS 128KB = 2 slots x (A 32KB + B 32KB).
// Per K-tile: 4 phases x {ds_read frags | stage | s_barrier | 16 MFMA | s_barrier},
// stage of KT i+2 into KT i's slot at phase 4 (provably after all reads),
// counted vmcnt(8) once per K-tile, never 0 in steady state.
// LDS XOR swizzle (T2): 16B-chunk c at row r holds global chunk c^(r&7);
// write side via pre-swizzled global source (lane-only: (l&7)^(l>>3)),
// read side applies the same XOR. setprio(1) around MFMA clusters (T5).
// ---------------------------------------------------------------------------
__global__ __launch_bounds__(512, 2)
void gemm_x_8ph(const __bf16* __restrict__ A, const __bf16* __restrict__ Bw,
                const float* __restrict__ bias, __bf16* __restrict__ X)
{
    __shared__ __bf16 lds[2][2][16384];   // [slot][A/B][256*64]

    const int tid  = threadIdx.x;
    const int lane = tid & 63;
    const int w    = tid >> 6;     // 0..7
    const int wm   = w >> 2;       // 0..1 -> 128 rows
    const int wn   = w & 3;        // 0..3 -> 64 cols

    const int bid  = blockIdx.x;                    // 1024 blocks, %8==0
    const int wgid = (bid & 7) * 128 + (bid >> 3);  // bijective XCD swizzle
    const int bm   = wgid >> 2;                     // 0..255
    const int bn   = wgid & 3;                      // 0..3
    const long row0 = (long)bm * 256;
    const long col0 = (long)bn * 256;

    // staging: thread covers rows j*64 + w*8 + (lane>>3), j=0..3, per matrix.
    // global col chunk pre-swizzled so linear LDS dest + swizzled read match.
    const int srow = w * 8 + (lane >> 3);
    const int scol = ((lane & 7) ^ (lane >> 3)) * 8;
    const __bf16* Ag = A  + (row0 + srow) * 1024 + scol;
    const __bf16* Bg = Bw + (col0 + srow) * 1024 + scol;
    const int ldst = w * 512;   // LDS dest elem base (+ j*4096), wave-uniform

    auto stage = [&](int kt, int sl) {
        const long ko = (long)kt * 64;
        #pragma unroll
        for (int j = 0; j < 4; ++j)
            __builtin_amdgcn_global_load_lds(
                (const __attribute__((address_space(1))) void*)(Ag + (long)j * 65536 + ko),
                (__attribute__((address_space(3))) void*)(&lds[sl][0][j * 4096 + ldst]),
                16, 0, 0);
        #pragma unroll
        for (int j = 0; j < 4; ++j)
            __builtin_amdgcn_global_load_lds(
                (const __attribute__((address_space(1))) void*)(Bg + (long)j * 65536 + ko),
                (__attribute__((address_space(3))) void*)(&lds[sl][1][j * 4096 + ldst]),
                16, 0, 0);
    };

    const int fr = lane & 15;
    const int g2 = lane >> 4;    // 0..3: 16B chunk within k-half
    const int x7 = lane & 7;     // read-side XOR key (= row&7 since row%16==fr)

    f32x4 acc[8][4];
    #pragma unroll
    for (int i = 0; i < 8; ++i)
        #pragma unroll
        for (int j = 0; j < 4; ++j)
            acc[i][j] = f32x4{0.f, 0.f, 0.f, 0.f};

    stage(0, 0);
    stage(1, 1);
    asm volatile("s_waitcnt vmcnt(8)" ::: "memory");   // KT0 landed, KT1 in flight
    __builtin_amdgcn_s_barrier();

    #pragma unroll 1
    for (int i = 0; i < 16; ++i) {
        const int s = i & 1;
        const __bf16* Al = &lds[s][0][0];
        const __bf16* Bl = &lds[s][1][0];

        bf16x8 a0[4][2], a1[4][2], b0[4], b1[4];

        // ---- P1: A m0-3 (k0,k1) + B k0; MFMA m0-3 x n0-3 x k0
        #pragma unroll
        for (int mi = 0; mi < 4; ++mi) {
            const int row = wm * 128 + mi * 16 + fr;
            a0[mi][0] = *(const bf16x8*)(Al + row * 64 + ((g2    ) ^ x7) * 8);
            a0[mi][1] = *(const bf16x8*)(Al + row * 64 + ((4 + g2) ^ x7) * 8);
        }
        #pragma unroll
        for (int ni = 0; ni < 4; ++ni) {
            const int row = wn * 64 + ni * 16 + fr;
            b0[ni] = *(const bf16x8*)(Bl + row * 64 + ((g2) ^ x7) * 8);
        }
        __builtin_amdgcn_s_barrier();
        __builtin_amdgcn_s_setprio(1);
        #pragma unroll
        for (int mi = 0; mi < 4; ++mi)
            #pragma unroll
            for (int ni = 0; ni < 4; ++ni)
                acc[mi][ni] = __builtin_amdgcn_mfma_f32_16x16x32_bf16(a0[mi][0], b0[ni], acc[mi][ni], 0, 0, 0);
        __builtin_amdgcn_s_setprio(0);
        __builtin_amdgcn_s_barrier();

        // ---- P2: B k1; MFMA m0-3 x n0-3 x k1
        #pragma unroll
        for (int ni = 0; ni < 4; ++ni) {
            const int row = wn * 64 + ni * 16 + fr;
            b1[ni] = *(const bf16x8*)(Bl + row * 64 + ((4 + g2) ^ x7) * 8);
        }
        __builtin_amdgcn_s_barrier();
        __builtin_amdgcn_s_setprio(1);
        #pragma unroll
        for (int mi = 0; mi < 4; ++mi)
            #pragma unroll
            for (int ni = 0; ni < 4; ++ni)
                acc[mi][ni] = __builtin_amdgcn_mfma_f32_16x16x32_bf16(a0[mi][1], b1[ni], acc[mi][ni], 0, 0, 0);
        __builtin_amdgcn_s_setprio(0);
        __builtin_amdgcn_s_barrier();

        // ---- P3: A m4-7 (k0,k1); MFMA m4-7 x n0-3 x k0  (last reads of slot s)
        #pragma unroll
        for (int mi = 0; mi < 4; ++mi) {
            const int row = wm * 128 + (mi + 4) * 16 + fr;
            a1[mi][0] = *(const bf16x8*)(Al + row * 64 + ((g2    ) ^ x7) * 8);
            a1[mi][1] = *(const bf16x8*)(Al + row * 64 + ((4 + g2) ^ x7) * 8);
        }
        __builtin_amdgcn_s_barrier();
        __builtin_amdgcn_s_setprio(1);
        #pragma unroll
        for (int mi = 0; mi < 4; ++mi)
            #pragma unroll
            for (int ni = 0; ni < 4; ++ni)
                acc[mi + 4][ni] = __builtin_amdgcn_mfma_f32_16x16x32_bf16(a1[mi][0], b0[ni], acc[mi + 4][ni], 0, 0, 0);
        __builtin_amdgcn_s_setprio(0);
        __builtin_amdgcn_s_barrier();

        // ---- P4: stage KT i+2 into slot s (all reads of s done + barrier'd);
        //         MFMA m4-7 x n0-3 x k1; counted vmcnt; barrier.
        if (i < 14) stage(i + 2, s);
        __builtin_amdgcn_s_barrier();
        __builtin_amdgcn_s_setprio(1);
        #pragma unroll
        for (int mi = 0; mi < 4; ++mi)
            #pragma unroll
            for (int ni = 0; ni < 4; ++ni)
                acc[mi + 4][ni] = __builtin_amdgcn_mfma_f32_16x16x32_bf16(a1[mi][1], b1[ni], acc[mi + 4][ni], 0, 0, 0);
        __builtin_amdgcn_s_setprio(0);
        if (i < 14) { asm volatile("s_waitcnt vmcnt(8)" ::: "memory"); }  // KT i+1 landed
        else        { asm volatile("s_waitcnt vmcnt(0)" ::: "memory"); }  // tail drain
        __builtin_amdgcn_s_barrier();
    }

    // epilogue: + bias(col), store bf16. C/D: col=lane&15, row=(lane>>4)*4+r
    const int g4 = lane >> 4;
    #pragma unroll
    for (int ni = 0; ni < 4; ++ni) {
        const long col = col0 + wn * 64 + ni * 16 + fr;
        const float bv = bias[col];
        #pragma unroll
        for (int mi = 0; mi < 8; ++mi) {
            #pragma unroll
            for (int r = 0; r < 4; ++r) {
                const long row = row0 + wm * 128 + mi * 16 + g4 * 4 + r;
                X[row * 1024 + col] = (__bf16)(acc[mi][ni][r] + bv);
            }
        }
    }
}

// ---------------------------------------------------------------------------
// K1 (fallback): reg-staged f32 GEMM, used only if ws too small.
// ---------------------------------------------------------------------------
__global__ __launch_bounds__(256, 2)
void gemm_x_kernel(const float* __restrict__ A, const float* __restrict__ Bw,
                   const float* __restrict__ bias, __bf16* __restrict__ X)
{
    __shared__ __bf16 As[128 * 32];
    __shared__ __bf16 Bs[128 * 32];
    const int tid  = threadIdx.x;
    const int lane = tid & 63;
    const int w    = tid >> 6;
    const int wr   = w >> 1;
    const int wc   = w & 1;
    const int bn   = blockIdx.x;
    const int bm   = blockIdx.y;
    const int row0 = bm * 128;
    const int col0 = bn * 128;
    const int srow = tid >> 2;
    const int sk8  = (tid & 3) * 8;
    f32x4 acc[4][4];
    #pragma unroll
    for (int i = 0; i < 4; ++i)
        #pragma unroll
        for (int j = 0; j < 4; ++j)
            acc[i][j] = f32x4{0.f, 0.f, 0.f, 0.f};
    const int fr = lane & 15;
    const int g8 = (lane >> 4) * 8;
    for (int kt = 0; kt < 32; ++kt) {
        const int k0 = kt * 32;
        const float* ap0 = A  + (row0 + srow) * 1024 + k0 + sk8;
        const float* ap1 = A  + (row0 + 64 + srow) * 1024 + k0 + sk8;
        const float* bp0 = Bw + (col0 + srow) * 1024 + k0 + sk8;
        const float* bp1 = Bw + (col0 + 64 + srow) * 1024 + k0 + sk8;
        float4 a00 = *(const float4*)ap0;
        float4 a01 = *(const float4*)(ap0 + 4);
        float4 a10 = *(const float4*)ap1;
        float4 a11 = *(const float4*)(ap1 + 4);
        float4 b00 = *(const float4*)bp0;
        float4 b01 = *(const float4*)(bp0 + 4);
        float4 b10 = *(const float4*)bp1;
        float4 b11 = *(const float4*)(bp1 + 4);
        __syncthreads();
        *(bf16x8*)(As + srow * 32 + sk8)        = cvt8(a00, a01);
        *(bf16x8*)(As + (64 + srow) * 32 + sk8) = cvt8(a10, a11);
        *(bf16x8*)(Bs + srow * 32 + sk8)        = cvt8(b00, b01);
        *(bf16x8*)(Bs + (64 + srow) * 32 + sk8) = cvt8(b10, b11);
        __syncthreads();
        bf16x8 af[4], bf[4];
        #pragma unroll
        for (int m = 0; m < 4; ++m)
            af[m] = *(const bf16x8*)(As + (wr * 64 + m * 16 + fr) * 32 + g8);
        #pragma unroll
        for (int n = 0; n < 4; ++n)
            bf[n] = *(const bf16x8*)(Bs + (wc * 64 + n * 16 + fr) * 32 + g8);
        #pragma unroll
        for (int m = 0; m < 4; ++m)
            #pragma unroll
            for (int n = 0; n < 4; ++n)
                acc[m][n] = __builtin_amdgcn_mfma_f32_16x16x32_bf16(af[m], bf[n], acc[m][n], 0, 0, 0);
    }
    const int g4 = lane >> 4;
    #pragma unroll
    for (int n = 0; n < 4; ++n) {
        const int col = col0 + wc * 64 + n * 16 + fr;
        const float bv = bias[col];
        #pragma unroll
        for (int m = 0; m < 4; ++m) {
            #pragma unroll
            for (int r = 0; r < 4; ++r) {
                const int row = row0 + wr * 64 + m * 16 + g4 * 4 + r;
                X[(long)row * 1024 + col] = (__bf16)(acc[m][n][r] + bv);
            }
        }
    }
}

// ---------------------------------------------------------------------------
// K2: partial sums over t for the time-mean. block = (tc, b), 1024 blocks.
// ---------------------------------------------------------------------------
__global__ __launch_bounds__(256)
void mean_part_k(const __bf16* __restrict__ X, float* __restrict__ mpart)
{
    const int bx = blockIdx.x;
    const int b  = bx & 31;
    const int tc = bx >> 5;
    const int j4 = threadIdx.x * 4;
    float a0 = 0.f, a1 = 0.f, a2 = 0.f, a3 = 0.f;
    #pragma unroll 4
    for (int i = 0; i < 64; ++i) {
        const int t = tc * 64 + i;
        bf16x4 v = *(const bf16x4*)(X + (long)(t * 32 + b) * 1024 + j4);
        a0 += (float)v[0]; a1 += (float)v[1]; a2 += (float)v[2]; a3 += (float)v[3];
    }
    float4* mp = (float4*)(mpart + ((long)tc * 32 + b) * 1024 + j4);
    *mp = make_float4(a0, a1, a2, a3);
}

// ---------------------------------------------------------------------------
// K3: finalize mean, gate2[b,h,q] = tanh(m . Wm[q] + bWm[q]). 32 blocks.
// ---------------------------------------------------------------------------
__global__ __launch_bounds__(256)
void gate2_k(const float* __restrict__ mpart, const float* __restrict__ Wm,
             const float* __restrict__ bWm, float* __restrict__ g2)
{
    __shared__ float mrow[1024];
    const int b = blockIdx.x;
    for (int j = threadIdx.x; j < 1024; j += 256) {
        float s = 0.f;
        #pragma unroll 8
        for (int tc = 0; tc < 32; ++tc) s += mpart[((long)tc * 32 + b) * 1024 + j];
        mrow[j] = s * (1.0f / 2048.0f);
    }
    __syncthreads();
    if (threadIdx.x < 128) {
        const int h = threadIdx.x >> 4;
        const int q = threadIdx.x & 15;
        float d = bWm[q];
        #pragma unroll 8
        for (int k = 0; k < 128; ++k) d += mrow[h * 128 + k] * Wm[q * 128 + k];
        g2[(b * 8 + h) * 16 + q] = tanhf(d);
    }
}

// ---------------------------------------------------------------------------
// K4: scores. X viewed as (524288 rows = bt*8+h, 128). One wave = 16 rows.
// ---------------------------------------------------------------------------
__global__ __launch_bounds__(256)
void scores_k(const __bf16* __restrict__ X, const float* __restrict__ W,
              const float* __restrict__ bW, const float* __restrict__ g2,
              const float* __restrict__ Wh, const float* __restrict__ bWh,
              float* __restrict__ sbuf)
{
    const int tid   = threadIdx.x;
    const int lane  = tid & 63;
    const int w     = tid >> 6;
    const int gw    = blockIdx.x * 4 + w;
    const int rbase = gw * 16;
    const int q     = lane & 15;
    const int g4    = lane >> 4;

    bf16x8 bfr[4];
    #pragma unroll
    for (int c = 0; c < 4; ++c) {
        const float* wp = W + q * 128 + c * 32 + g4 * 8;
        float4 w0 = *(const float4*)wp;
        float4 w1 = *(const float4*)(wp + 4);
        bfr[c] = cvt8(w0, w1);
    }
    const __bf16* xp = X + (long)(rbase + q) * 128 + g4 * 8;
    bf16x8 afr[4];
    #pragma unroll
    for (int c = 0; c < 4; ++c) afr[c] = *(const bf16x8*)(xp + c * 32);

    f32x4 acc = f32x4{0.f, 0.f, 0.f, 0.f};
    #pragma unroll
    for (int c = 0; c < 4; ++c)
        acc = __builtin_amdgcn_mfma_f32_16x16x32_bf16(afr[c], bfr[c], acc, 0, 0, 0);

    const float whq  = Wh[q];
    const float bWv  = bW[q];
    const float bWhv = *bWh;
    #pragma unroll
    for (int r = 0; r < 4; ++r) {
        const int row = rbase + g4 * 4 + r;
        const int h   = row & 7;
        const int bt  = row >> 3;
        const int b   = bt & 31;
        const int t   = bt >> 5;
        float val = tanhf(acc[r] + bWv) * g2[(b * 8 + h) * 16 + q] * whq;
        val += __shfl_xor(val, 1);
        val += __shfl_xor(val, 2);
        val += __shfl_xor(val, 4);
        val += __shfl_xor(val, 8);
        if (q == 0) sbuf[(b * 8 + h) * 2048 + t] = val + bWhv;
    }
}

// ---------------------------------------------------------------------------
// K5: softmax over t, in place. 256 blocks (b*8+h).
// ---------------------------------------------------------------------------
__global__ __launch_bounds__(256)
void softmax_k(float* __restrict__ s)
{
    __shared__ float red[256];
    const int bh = blockIdx.x;
    const int tid = threadIdx.x;
    float* row = s + bh * 2048;
    float4 v0 = *(const float4*)(row + tid * 8);
    float4 v1 = *(const float4*)(row + tid * 8 + 4);
    float v[8] = {v0.x, v0.y, v0.z, v0.w, v1.x, v1.y, v1.z, v1.w};
    float mx = v[0];
    #pragma unroll
    for (int i = 1; i < 8; ++i) mx = fmaxf(mx, v[i]);
    red[tid] = mx;
    __syncthreads();
    for (int st = 128; st > 0; st >>= 1) {
        if (tid < st) red[tid] = fmaxf(red[tid], red[tid + st]);
        __syncthreads();
    }
    mx = red[0];
    __syncthreads();
    float sum = 0.f;
    #pragma unroll
    for (int i = 0; i < 8; ++i) { v[i] = expf(v[i] - mx); sum += v[i]; }
    red[tid] = sum;
    __syncthreads();
    for (int st = 128; st > 0; st >>= 1) {
        if (tid < st) red[tid] += red[tid + st];
        __syncthreads();
    }
    const float inv = 1.0f / red[0];
    *(float4*)(row + tid * 8)     = make_float4(v[0] * inv, v[1] * inv, v[2] * inv, v[3] * inv);
    *(float4*)(row + tid * 8 + 4) = make_float4(v[4] * inv, v[5] * inv, v[6] * inv, v[7] * inv);
}

// ---------------------------------------------------------------------------
// K6: weighted sum over t, t split 8 ways. 2048 blocks.
// ---------------------------------------------------------------------------
__global__ __launch_bounds__(256)
void wsum_k(const float* __restrict__ a, const __bf16* __restrict__ X,
            float* __restrict__ wpart)
{
    __shared__ float pk[8 * 128];
    const int bx = blockIdx.x;
    const int tc = bx & 7;
    const int bh = bx >> 3;
    const int b  = bh >> 3;
    const int h  = bh & 7;
    const int tid = threadIdx.x;
    const int kq = tid & 31;
    const int tr = tid >> 5;
    const float* ar = a + bh * 2048 + tc * 256;
    float a0 = 0.f, a1 = 0.f, a2 = 0.f, a3 = 0.f;
    #pragma unroll 4
    for (int i = tr; i < 256; i += 8) {
        const int t = tc * 256 + i;
        const float av = ar[i];
        bf16x4 xv = *(const bf16x4*)(X + (long)(t * 32 + b) * 1024 + h * 128 + kq * 4);
        a0 += av * (float)xv[0];
        a1 += av * (float)xv[1];
        a2 += av * (float)xv[2];
        a3 += av * (float)xv[3];
    }
    pk[tr * 128 + kq * 4 + 0] = a0;
    pk[tr * 128 + kq * 4 + 1] = a1;
    pk[tr * 128 + kq * 4 + 2] = a2;
    pk[tr * 128 + kq * 4 + 3] = a3;
    __syncthreads();
    if (tid < 128) {
        float s2 = 0.f;
        #pragma unroll
        for (int r = 0; r < 8; ++r) s2 += pk[r * 128 + tid];
        wpart[(long)bx * 128 + tid] = s2;
    }
}

// K7: reduce the 8 t-chunks.
__global__ __launch_bounds__(256)
void wsum_fin(const float* __restrict__ wpart, float* __restrict__ out)
{
    const int idx = blockIdx.x * 256 + threadIdx.x;
    const int k  = idx & 127;
    const int bh = idx >> 7;
    const int b  = bh >> 3;
    const int h  = bh & 7;
    float s = 0.f;
    #pragma unroll
    for (int tc = 0; tc < 8; ++tc) s += wpart[(bh * 8 + tc) * 128 + k];
    out[b * 1024 + h * 128 + k] = s;
}

extern "C" void kernel_launch(void* const* d_in, const int* in_sizes, int n_in,
                              void* d_out, int out_size, void* d_ws, size_t ws_size,
                              hipStream_t stream)
{
    const float* hyp = (const float*)d_in[0];
    const float* Wmh = (const float*)d_in[1];
    const float* bmh = (const float*)d_in[2];
    const float* W   = (const float*)d_in[3];
    const float* bW  = (const float*)d_in[4];
    const float* Wm  = (const float*)d_in[5];
    const float* bWm = (const float*)d_in[6];
    const float* Wh  = (const float*)d_in[7];
    const float* bWh = (const float*)d_in[8];
    float* out = (float*)d_out;

    char* ws = (char*)d_ws;
    const size_t SZ_X   = 134217728;   // 65536*1024*2
    const size_t SZ_AB  = 134217728;   // bf16 hyp
    const size_t SZ_BB  = 2097152;     // bf16 Wmh
    const size_t SZ_MP  = 4194304;
    const size_t SZ_G2  = 16384;
    const size_t SZ_SB  = 2097152;
    const size_t SZ_WP  = 1048576;
    const size_t need_fast = SZ_X + SZ_AB + SZ_BB + SZ_MP + SZ_G2 + SZ_SB + SZ_WP;

    __bf16* X;
    float *mpart, *g2, *sbuf, *wpart;

    if (ws_size >= need_fast) {
        X              = (__bf16*)(ws);
        __bf16* Ab     = (__bf16*)(ws + SZ_X);
        __bf16* Bb     = (__bf16*)(ws + SZ_X + SZ_AB);
        mpart = (float*)(ws + SZ_X + SZ_AB + SZ_BB);
        g2    = (float*)(ws + SZ_X + SZ_AB + SZ_BB + SZ_MP);
        sbuf  = (float*)(ws + SZ_X + SZ_AB + SZ_BB + SZ_MP + SZ_G2);
        wpart = (float*)(ws + SZ_X + SZ_AB + SZ_BB + SZ_MP + SZ_G2 + SZ_SB);

        cvt_f32_bf16<<<32768, 256, 0, stream>>>(hyp, Ab);
        cvt_f32_bf16<<<512,   256, 0, stream>>>(Wmh, Bb);
        gemm_x_8ph<<<1024, 512, 0, stream>>>(Ab, Bb, bmh, X);
    } else {
        X     = (__bf16*)(ws);
        mpart = (float*)(ws + SZ_X);
        g2    = (float*)(ws + SZ_X + SZ_MP);
        sbuf  = (float*)(ws + SZ_X + SZ_MP + SZ_G2);
        wpart = (float*)(ws + SZ_X + SZ_MP + SZ_G2 + SZ_SB);
        gemm_x_kernel<<<dim3(8, 512), 256, 0, stream>>>(hyp, Wmh, bmh, X);
    }

    mean_part_k<<<1024, 256, 0, stream>>>(X, mpart);
    gate2_k<<<32, 256, 0, stream>>>(mpart, Wm, bWm, g2);
    scores_k<<<8192, 256, 0, stream>>>(X, W, bW, g2, Wh, bWh, sbuf);
    softmax_k<<<256, 256, 0, stream>>>(sbuf);
    wsum_k<<<2048, 256, 0, stream>>>(sbuf, X, wpart);
    wsum_fin<<<128, 256, 0, stream>>>(wpart, out);
}

// Round 4
// 346.724 us; speedup vs baseline: 1.2325x; 1.0417x over previous
//
#include <hip/hip_runtime.h>
#include <hip/hip_bf16.h>

// Problem constants (T=2048, B=32, N=1024, H=8, K=128, K2=16)
#define T_DIM 2048
#define B_DIM 32
#define N_DIM 1024
#define H_DIM 8
#define K_DIM 128
#define Q_DIM 16

typedef __bf16 bf16x8 __attribute__((ext_vector_type(8)));
typedef __bf16 bf16x4 __attribute__((ext_vector_type(4)));
typedef float  f32x4  __attribute__((ext_vector_type(4)));

__device__ inline bf16x8 cvt8(float4 a, float4 b) {
    bf16x8 r;
    r[0] = (__bf16)a.x; r[1] = (__bf16)a.y; r[2] = (__bf16)a.z; r[3] = (__bf16)a.w;
    r[4] = (__bf16)b.x; r[5] = (__bf16)b.y; r[6] = (__bf16)b.z; r[7] = (__bf16)b.w;
    return r;
}

// ---------------------------------------------------------------------------
// K0: f32 -> bf16 convert, 8 elems/thread.
// ---------------------------------------------------------------------------
__global__ __launch_bounds__(256)
void cvt_f32_bf16(const float* __restrict__ s, __bf16* __restrict__ d)
{
    const long i = ((long)blockIdx.x * 256 + threadIdx.x) * 8;
    float4 a = *(const float4*)(s + i);
    float4 b = *(const float4*)(s + i + 4);
    *(bf16x8*)(d + i) = cvt8(a, b);
}

// ---------------------------------------------------------------------------
// K1: 256x256-tile 8-phase GEMM, operand-SWAPPED MFMA (acc holds D^T frags:
// lane&15 = X-row, (lane>>4)*4+j = X-col) -> coalesced bf16x4 stores, and
// lane-local time-mean partials fused into the epilogue.
// 8 waves (2M x 4N), BK=64, LDS 128KB = 2 slots x (A 32KB + B 32KB).
// Reads 8/8/8/0 per phase; stage of KT i+2 at P4 (slot fully read);
// counted vmcnt(8); XOR-swizzled LDS (T2); setprio around MFMA (T5).
// ---------------------------------------------------------------------------
__global__ __launch_bounds__(512, 2)
void gemm_x_8ph(const __bf16* __restrict__ A, const __bf16* __restrict__ Bw,
                const float* __restrict__ bias, __bf16* __restrict__ X,
                float* __restrict__ mpart)
{
    __shared__ __bf16 lds[2][2][16384];   // [slot][A/B][256*64]

    const int tid  = threadIdx.x;
    const int lane = tid & 63;
    const int w    = tid >> 6;     // 0..7
    const int wm   = w >> 2;       // 0..1 -> 128 rows
    const int wn   = w & 3;        // 0..3 -> 64 cols

    const int bid  = blockIdx.x;                    // 1024 blocks, %8==0
    const int wgid = (bid & 7) * 128 + (bid >> 3);  // bijective XCD swizzle
    const int bm   = wgid >> 2;                     // 0..255
    const int bn   = wgid & 3;                      // 0..3
    const long row0 = (long)bm * 256;
    const long col0 = (long)bn * 256;

    // staging: thread covers rows j*64 + w*8 + (lane>>3), j=0..3, per matrix.
    // global col chunk pre-swizzled so linear LDS dest + swizzled read match.
    const int srow = w * 8 + (lane >> 3);
    const int scol = ((lane & 7) ^ (lane >> 3)) * 8;
    const __bf16* Ag = A  + (row0 + srow) * 1024 + scol;
    const __bf16* Bg = Bw + (col0 + srow) * 1024 + scol;
    const int ldst = w * 512;   // LDS dest elem base (+ j*4096), wave-uniform

    auto stage = [&](int kt, int sl) {
        const long ko = (long)kt * 64;
        #pragma unroll
        for (int j = 0; j < 4; ++j)
            __builtin_amdgcn_global_load_lds(
                (const __attribute__((address_space(1))) void*)(Ag + (long)j * 65536 + ko),
                (__attribute__((address_space(3))) void*)(&lds[sl][0][j * 4096 + ldst]),
                16, 0, 0);
        #pragma unroll
        for (int j = 0; j < 4; ++j)
            __builtin_amdgcn_global_load_lds(
                (const __attribute__((address_space(1))) void*)(Bg + (long)j * 65536 + ko),
                (__attribute__((address_space(3))) void*)(&lds[sl][1][j * 4096 + ldst]),
                16, 0, 0);
    };

    const int fr = lane & 15;
    const int g2 = lane >> 4;    // 0..3: 16B chunk within k-half
    const int x7 = lane & 7;     // read-side XOR key

    f32x4 acc[8][4];
    #pragma unroll
    for (int i = 0; i < 8; ++i)
        #pragma unroll
        for (int j = 0; j < 4; ++j)
            acc[i][j] = f32x4{0.f, 0.f, 0.f, 0.f};

    stage(0, 0);
    stage(1, 1);
    asm volatile("s_waitcnt vmcnt(8)" ::: "memory");   // KT0 landed
    __builtin_amdgcn_s_barrier();

    #pragma unroll 1
    for (int i = 0; i < 16; ++i) {
        const int s = i & 1;
        const __bf16* Al = &lds[s][0][0];
        const __bf16* Bl = &lds[s][1][0];

        bf16x8 a0[4], a0h[4], a1[4], a1h[4], b0[4], b1[4];

        // ---- P1: reads a0(k0) + b0(k0); MFMA m0-3 x k0 (swapped operands)
        #pragma unroll
        for (int mi = 0; mi < 4; ++mi) {
            const int row = wm * 128 + mi * 16 + fr;
            a0[mi] = *(const bf16x8*)(Al + row * 64 + ((g2) ^ x7) * 8);
        }
        #pragma unroll
        for (int ni = 0; ni < 4; ++ni) {
            const int row = wn * 64 + ni * 16 + fr;
            b0[ni] = *(const bf16x8*)(Bl + row * 64 + ((g2) ^ x7) * 8);
        }
        __builtin_amdgcn_s_barrier();
        __builtin_amdgcn_s_setprio(1);
        #pragma unroll
        for (int mi = 0; mi < 4; ++mi)
            #pragma unroll
            for (int ni = 0; ni < 4; ++ni)
                acc[mi][ni] = __builtin_amdgcn_mfma_f32_16x16x32_bf16(b0[ni], a0[mi], acc[mi][ni], 0, 0, 0);
        __builtin_amdgcn_s_setprio(0);
        __builtin_amdgcn_s_barrier();

        // ---- P2: reads a0(k1) + b1(k1); MFMA m0-3 x k1
        #pragma unroll
        for (int mi = 0; mi < 4; ++mi) {
            const int row = wm * 128 + mi * 16 + fr;
            a0h[mi] = *(const bf16x8*)(Al + row * 64 + ((4 + g2) ^ x7) * 8);
        }
        #pragma unroll
        for (int ni = 0; ni < 4; ++ni) {
            const int row = wn * 64 + ni * 16 + fr;
            b1[ni] = *(const bf16x8*)(Bl + row * 64 + ((4 + g2) ^ x7) * 8);
        }
        __builtin_amdgcn_s_barrier();
        __builtin_amdgcn_s_setprio(1);
        #pragma unroll
        for (int mi = 0; mi < 4; ++mi)
            #pragma unroll
            for (int ni = 0; ni < 4; ++ni)
                acc[mi][ni] = __builtin_amdgcn_mfma_f32_16x16x32_bf16(b1[ni], a0h[mi], acc[mi][ni], 0, 0, 0);
        __builtin_amdgcn_s_setprio(0);
        __builtin_amdgcn_s_barrier();

        // ---- P3: reads a1(k0) + a1(k1); MFMA m4-7 x k0
        #pragma unroll
        for (int mi = 0; mi < 4; ++mi) {
            const int row = wm * 128 + (mi + 4) * 16 + fr;
            a1[mi]  = *(const bf16x8*)(Al + row * 64 + ((g2    ) ^ x7) * 8);
            a1h[mi] = *(const bf16x8*)(Al + row * 64 + ((4 + g2) ^ x7) * 8);
        }
        __builtin_amdgcn_s_barrier();
        __builtin_amdgcn_s_setprio(1);
        #pragma unroll
        for (int mi = 0; mi < 4; ++mi)
            #pragma unroll
            for (int ni = 0; ni < 4; ++ni)
                acc[mi + 4][ni] = __builtin_amdgcn_mfma_f32_16x16x32_bf16(b0[ni], a1[mi], acc[mi + 4][ni], 0, 0, 0);
        __builtin_amdgcn_s_setprio(0);
        __builtin_amdgcn_s_barrier();

        // ---- P4: stage KT i+2 into slot s; MFMA m4-7 x k1; counted vmcnt.
        if (i < 14) stage(i + 2, s);
        __builtin_amdgcn_s_barrier();
        __builtin_amdgcn_s_setprio(1);
        #pragma unroll
        for (int mi = 0; mi < 4; ++mi)
            #pragma unroll
            for (int ni = 0; ni < 4; ++ni)
                acc[mi + 4][ni] = __builtin_amdgcn_mfma_f32_16x16x32_bf16(b1[ni], a1h[mi], acc[mi + 4][ni], 0, 0, 0);
        __builtin_amdgcn_s_setprio(0);
        if (i < 14) { asm volatile("s_waitcnt vmcnt(8)" ::: "memory"); }
        else        { asm volatile("s_waitcnt vmcnt(0)" ::: "memory"); }
        __builtin_amdgcn_s_barrier();
    }

    // ------------------ epilogue ------------------
    // Transposed D: element (row = wm*128+mi*16+fr, col = wn*64+ni*16+g4*4+j).
    // One bf16x4 store per (mi,ni). Lane-local mean partial: b = row%32 =
    // fr + 16*(mi&1); msum[mi&1][ni][j] accumulates X over this thread's rows.
    const int g4 = lane >> 4;
    const long colb = col0 + wn * 64 + g4 * 4;

    float4 bias4[4];
    #pragma unroll
    for (int ni = 0; ni < 4; ++ni)
        bias4[ni] = *(const float4*)(bias + colb + ni * 16);

    f32x4 msum[2][4];
    #pragma unroll
    for (int bh = 0; bh < 2; ++bh)
        #pragma unroll
        for (int ni = 0; ni < 4; ++ni)
            msum[bh][ni] = f32x4{0.f, 0.f, 0.f, 0.f};

    #pragma unroll
    for (int mi = 0; mi < 8; ++mi) {
        const long row = row0 + wm * 128 + mi * 16 + fr;
        #pragma unroll
        for (int ni = 0; ni < 4; ++ni) {
            f32x4 xv;
            xv[0] = acc[mi][ni][0] + bias4[ni].x;
            xv[1] = acc[mi][ni][1] + bias4[ni].y;
            xv[2] = acc[mi][ni][2] + bias4[ni].z;
            xv[3] = acc[mi][ni][3] + bias4[ni].w;
            bf16x4 xb;
            xb[0] = (__bf16)xv[0]; xb[1] = (__bf16)xv[1];
            xb[2] = (__bf16)xv[2]; xb[3] = (__bf16)xv[3];
            *(bf16x4*)(X + row * 1024 + colb + ni * 16) = xb;
            msum[mi & 1][ni] += xv;
        }
    }

    // cross-wave (wm) reduce of mean partials through LDS (free after K-loop)
    float* ldsf = (float*)&lds[0][0][0];    // 32 b x 256 n f32 = 32 KB
    __syncthreads();                        // all K-loop LDS traffic done
    if (wm == 1) {
        #pragma unroll
        for (int bh = 0; bh < 2; ++bh)
            #pragma unroll
            for (int ni = 0; ni < 4; ++ni)
                *(f32x4*)(ldsf + (bh * 16 + fr) * 256 + wn * 64 + ni * 16 + g4 * 4) = msum[bh][ni];
    }
    __syncthreads();
    if (wm == 0) {
        #pragma unroll
        for (int bh = 0; bh < 2; ++bh) {
            const int b = bh * 16 + fr;
            #pragma unroll
            for (int ni = 0; ni < 4; ++ni) {
                f32x4 other = *(const f32x4*)(ldsf + b * 256 + wn * 64 + ni * 16 + g4 * 4);
                f32x4 tot = msum[bh][ni] + other;
                *(f32x4*)(mpart + ((long)bm * 32 + b) * 1024 + colb + ni * 16) = tot;
            }
        }
    }
}

// ---------------------------------------------------------------------------
// K3: finalize mean from fused partials, gate2[b,h,q] = tanh(m.Wm[q]+bWm[q]).
// ---------------------------------------------------------------------------
__global__ __launch_bounds__(256)
void gate2_k(const float* __restrict__ mpart, const float* __restrict__ Wm,
             const float* __restrict__ bWm, float* __restrict__ g2)
{
    __shared__ float mrow[1024];
    const int b = blockIdx.x;
    const int j4 = threadIdx.x * 4;
    f32x4 s = f32x4{0.f, 0.f, 0.f, 0.f};
    for (int bm = 0; bm < 256; ++bm)
        s += *(const f32x4*)(mpart + ((long)bm * 32 + b) * 1024 + j4);
    mrow[j4 + 0] = s[0] * (1.0f / 2048.0f);
    mrow[j4 + 1] = s[1] * (1.0f / 2048.0f);
    mrow[j4 + 2] = s[2] * (1.0f / 2048.0f);
    mrow[j4 + 3] = s[3] * (1.0f / 2048.0f);
    __syncthreads();
    if (threadIdx.x < 128) {
        const int h = threadIdx.x >> 4;
        const int q = threadIdx.x & 15;
        float d = bWm[q];
        #pragma unroll 8
        for (int k = 0; k < 128; ++k) d += mrow[h * 128 + k] * Wm[q * 128 + k];
        g2[(b * 8 + h) * 16 + q] = tanhf(d);
    }
}

// ---------------------------------------------------------------------------
// K4: scores. X viewed as (524288 rows = bt*8+h, 128). One wave = 16 rows.
// ---------------------------------------------------------------------------
__global__ __launch_bounds__(256)
void scores_k(const __bf16* __restrict__ X, const float* __restrict__ W,
              const float* __restrict__ bW, const float* __restrict__ g2,
              const float* __restrict__ Wh, const float* __restrict__ bWh,
              float* __restrict__ sbuf)
{
    const int tid   = threadIdx.x;
    const int lane  = tid & 63;
    const int w     = tid >> 6;
    const int gw    = blockIdx.x * 4 + w;
    const int rbase = gw * 16;
    const int q     = lane & 15;
    const int g4    = lane >> 4;

    bf16x8 bfr[4];
    #pragma unroll
    for (int c = 0; c < 4; ++c) {
        const float* wp = W + q * 128 + c * 32 + g4 * 8;
        float4 w0 = *(const float4*)wp;
        float4 w1 = *(const float4*)(wp + 4);
        bfr[c] = cvt8(w0, w1);
    }
    const __bf16* xp = X + (long)(rbase + q) * 128 + g4 * 8;
    bf16x8 afr[4];
    #pragma unroll
    for (int c = 0; c < 4; ++c) afr[c] = *(const bf16x8*)(xp + c * 32);

    f32x4 acc = f32x4{0.f, 0.f, 0.f, 0.f};
    #pragma unroll
    for (int c = 0; c < 4; ++c)
        acc = __builtin_amdgcn_mfma_f32_16x16x32_bf16(afr[c], bfr[c], acc, 0, 0, 0);

    const float whq  = Wh[q];
    const float bWv  = bW[q];
    const float bWhv = *bWh;
    #pragma unroll
    for (int r = 0; r < 4; ++r) {
        const int row = rbase + g4 * 4 + r;
        const int h   = row & 7;
        const int bt  = row >> 3;
        const int b   = bt & 31;
        const int t   = bt >> 5;
        float val = tanhf(acc[r] + bWv) * g2[(b * 8 + h) * 16 + q] * whq;
        val += __shfl_xor(val, 1);
        val += __shfl_xor(val, 2);
        val += __shfl_xor(val, 4);
        val += __shfl_xor(val, 8);
        if (q == 0) sbuf[(b * 8 + h) * 2048 + t] = val + bWhv;
    }
}

// ---------------------------------------------------------------------------
// K5: softmax over t, in place. 256 blocks (b*8+h).
// ---------------------------------------------------------------------------
__global__ __launch_bounds__(256)
void softmax_k(float* __restrict__ s)
{
    __shared__ float red[256];
    const int bh = blockIdx.x;
    const int tid = threadIdx.x;
    float* row = s + bh * 2048;
    float4 v0 = *(const float4*)(row + tid * 8);
    float4 v1 = *(const float4*)(row + tid * 8 + 4);
    float v[8] = {v0.x, v0.y, v0.z, v0.w, v1.x, v1.y, v1.z, v1.w};
    float mx = v[0];
    #pragma unroll
    for (int i = 1; i < 8; ++i) mx = fmaxf(mx, v[i]);
    red[tid] = mx;
    __syncthreads();
    for (int st = 128; st > 0; st >>= 1) {
        if (tid < st) red[tid] = fmaxf(red[tid], red[tid + st]);
        __syncthreads();
    }
    mx = red[0];
    __syncthreads();
    float sum = 0.f;
    #pragma unroll
    for (int i = 0; i < 8; ++i) { v[i] = expf(v[i] - mx); sum += v[i]; }
    red[tid] = sum;
    __syncthreads();
    for (int st = 128; st > 0; st >>= 1) {
        if (tid < st) red[tid] += red[tid + st];
        __syncthreads();
    }
    const float inv = 1.0f / red[0];
    *(float4*)(row + tid * 8)     = make_float4(v[0] * inv, v[1] * inv, v[2] * inv, v[3] * inv);
    *(float4*)(row + tid * 8 + 4) = make_float4(v[4] * inv, v[5] * inv, v[6] * inv, v[7] * inv);
}

// ---------------------------------------------------------------------------
// K6: weighted sum over t, t split 8 ways. 2048 blocks.
// ---------------------------------------------------------------------------
__global__ __launch_bounds__(256)
void wsum_k(const float* __restrict__ a, const __bf16* __restrict__ X,
            float* __restrict__ wpart)
{
    __shared__ float pk[8 * 128];
    const int bx = blockIdx.x;
    const int tc = bx & 7;
    const int bh = bx >> 3;
    const int b  = bh >> 3;
    const int h  = bh & 7;
    const int tid = threadIdx.x;
    const int kq = tid & 31;
    const int tr = tid >> 5;
    const float* ar = a + bh * 2048 + tc * 256;
    float a0 = 0.f, a1 = 0.f, a2 = 0.f, a3 = 0.f;
    #pragma unroll 4
    for (int i = tr; i < 256; i += 8) {
        const int t = tc * 256 + i;
        const float av = ar[i];
        bf16x4 xv = *(const bf16x4*)(X + (long)(t * 32 + b) * 1024 + h * 128 + kq * 4);
        a0 += av * (float)xv[0];
        a1 += av * (float)xv[1];
        a2 += av * (float)xv[2];
        a3 += av * (float)xv[3];
    }
    pk[tr * 128 + kq * 4 + 0] = a0;
    pk[tr * 128 + kq * 4 + 1] = a1;
    pk[tr * 128 + kq * 4 + 2] = a2;
    pk[tr * 128 + kq * 4 + 3] = a3;
    __syncthreads();
    if (tid < 128) {
        float s2 = 0.f;
        #pragma unroll
        for (int r = 0; r < 8; ++r) s2 += pk[r * 128 + tid];
        wpart[(long)bx * 128 + tid] = s2;
    }
}

// K7: reduce the 8 t-chunks.
__global__ __launch_bounds__(256)
void wsum_fin(const float* __restrict__ wpart, float* __restrict__ out)
{
    const int idx = blockIdx.x * 256 + threadIdx.x;
    const int k  = idx & 127;
    const int bh = idx >> 7;
    const int b  = bh >> 3;
    const int h  = bh & 7;
    float s = 0.f;
    #pragma unroll
    for (int tc = 0; tc < 8; ++tc) s += wpart[(bh * 8 + tc) * 128 + k];
    out[b * 1024 + h * 128 + k] = s;
}

extern "C" void kernel_launch(void* const* d_in, const int* in_sizes, int n_in,
                              void* d_out, int out_size, void* d_ws, size_t ws_size,
                              hipStream_t stream)
{
    const float* hyp = (const float*)d_in[0];
    const float* Wmh = (const float*)d_in[1];
    const float* bmh = (const float*)d_in[2];
    const float* W   = (const float*)d_in[3];
    const float* bW  = (const float*)d_in[4];
    const float* Wm  = (const float*)d_in[5];
    const float* bWm = (const float*)d_in[6];
    const float* Wh  = (const float*)d_in[7];
    const float* bWh = (const float*)d_in[8];
    float* out = (float*)d_out;

    char* ws = (char*)d_ws;
    const size_t SZ_X   = 134217728;   // X bf16 (65536 x 1024)
    const size_t SZ_AB  = 134217728;   // Ab bf16 hyp
    const size_t SZ_BB  = 2097152;     // Bb bf16 Wmh
    const size_t SZ_MP  = 33554432;    // mpart f32 (256 x 32 x 1024)
    const size_t SZ_G2  = 16384;
    const size_t SZ_SB  = 2097152;

    size_t off = 0;
    __bf16* X     = (__bf16*)(ws + off); off += SZ_X;
    __bf16* Ab    = (__bf16*)(ws + off); off += SZ_AB;
    __bf16* Bb    = (__bf16*)(ws + off); off += SZ_BB;
    float*  mpart = (float*) (ws + off); off += SZ_MP;
    float*  g2    = (float*) (ws + off); off += SZ_G2;
    float*  sbuf  = (float*) (ws + off); off += SZ_SB;
    float*  wpart = (float*) (ws + off);

    cvt_f32_bf16<<<32768, 256, 0, stream>>>(hyp, Ab);
    cvt_f32_bf16<<<512,   256, 0, stream>>>(Wmh, Bb);
    gemm_x_8ph<<<1024, 512, 0, stream>>>(Ab, Bb, bmh, X, mpart);
    gate2_k<<<32, 256, 0, stream>>>(mpart, Wm, bWm, g2);
    scores_k<<<8192, 256, 0, stream>>>(X, W, bW, g2, Wh, bWh, sbuf);
    softmax_k<<<256, 256, 0, stream>>>(sbuf);
    wsum_k<<<2048, 256, 0, stream>>>(sbuf, X, wpart);
    wsum_fin<<<128, 256, 0, stream>>>(wpart, out);
}

// Round 5
// 329.510 us; speedup vs baseline: 1.2969x; 1.0522x over previous
//
#include <hip/hip_runtime.h>
#include <hip/hip_bf16.h>

// Problem constants (T=2048, B=32, N=1024, H=8, K=128, K2=16)
#define T_DIM 2048
#define B_DIM 32
#define N_DIM 1024
#define H_DIM 8
#define K_DIM 128
#define Q_DIM 16

typedef __bf16 bf16x8 __attribute__((ext_vector_type(8)));
typedef __bf16 bf16x4 __attribute__((ext_vector_type(4)));
typedef float  f32x4  __attribute__((ext_vector_type(4)));

__device__ inline bf16x8 cvt8(float4 a, float4 b) {
    bf16x8 r;
    r[0] = (__bf16)a.x; r[1] = (__bf16)a.y; r[2] = (__bf16)a.z; r[3] = (__bf16)a.w;
    r[4] = (__bf16)b.x; r[5] = (__bf16)b.y; r[6] = (__bf16)b.z; r[7] = (__bf16)b.w;
    return r;
}

// ---------------------------------------------------------------------------
// K0: f32 -> bf16 convert, 8 elems/thread.
// ---------------------------------------------------------------------------
__global__ __launch_bounds__(256)
void cvt_f32_bf16(const float* __restrict__ s, __bf16* __restrict__ d)
{
    const long i = ((long)blockIdx.x * 256 + threadIdx.x) * 8;
    float4 a = *(const float4*)(s + i);
    float4 b = *(const float4*)(s + i + 4);
    *(bf16x8*)(d + i) = cvt8(a, b);
}

// ---------------------------------------------------------------------------
// K1: 256x256-tile GEMM, operand-swapped MFMA, SOFTWARE-PIPELINED LDS reads:
// read-group for MFMA-group g+1 issued before MFMA-group g (separate regs),
// so compiler-emitted counted lgkmcnt lets each MFMA cluster hide the next
// cluster's LDS drain. 2 barriers per K-tile (slot-reuse + stage-landed).
// Counted vmcnt(8) (T4); XOR-swizzled LDS (T2); setprio (T5).
// Fused time-mean partials in epilogue; coalesced bf16x4 stores.
// ---------------------------------------------------------------------------
__global__ __launch_bounds__(512, 2)
void gemm_x_8ph(const __bf16* __restrict__ A, const __bf16* __restrict__ Bw,
                const float* __restrict__ bias, __bf16* __restrict__ X,
                float* __restrict__ mpart)
{
    __shared__ __bf16 lds[2][2][16384];   // [slot][A/B][256*64]

    const int tid  = threadIdx.x;
    const int lane = tid & 63;
    const int w    = tid >> 6;     // 0..7
    const int wm   = w >> 2;       // 0..1 -> 128 rows
    const int wn   = w & 3;        // 0..3 -> 64 cols

    const int bid  = blockIdx.x;                    // 1024 blocks, %8==0
    const int wgid = (bid & 7) * 128 + (bid >> 3);  // bijective XCD swizzle
    const int bm   = wgid >> 2;                     // 0..255
    const int bn   = wgid & 3;                      // 0..3
    const long row0 = (long)bm * 256;
    const long col0 = (long)bn * 256;

    // staging: thread covers rows j*64 + w*8 + (lane>>3), j=0..3, per matrix.
    // global col chunk pre-swizzled so linear LDS dest + swizzled read match.
    const int srow = w * 8 + (lane >> 3);
    const int scol = ((lane & 7) ^ (lane >> 3)) * 8;
    const __bf16* Ag = A  + (row0 + srow) * 1024 + scol;
    const __bf16* Bg = Bw + (col0 + srow) * 1024 + scol;
    const int ldst = w * 512;   // LDS dest elem base (+ j*4096), wave-uniform

    auto stage = [&](int kt, int sl) {
        const long ko = (long)kt * 64;
        #pragma unroll
        for (int j = 0; j < 4; ++j)
            __builtin_amdgcn_global_load_lds(
                (const __attribute__((address_space(1))) void*)(Ag + (long)j * 65536 + ko),
                (__attribute__((address_space(3))) void*)(&lds[sl][0][j * 4096 + ldst]),
                16, 0, 0);
        #pragma unroll
        for (int j = 0; j < 4; ++j)
            __builtin_amdgcn_global_load_lds(
                (const __attribute__((address_space(1))) void*)(Bg + (long)j * 65536 + ko),
                (__attribute__((address_space(3))) void*)(&lds[sl][1][j * 4096 + ldst]),
                16, 0, 0);
    };

    const int fr = lane & 15;
    const int g2 = lane >> 4;    // 0..3: 16B chunk within k-half
    const int x7 = lane & 7;     // read-side XOR key

    f32x4 acc[8][4];
    #pragma unroll
    for (int i = 0; i < 8; ++i)
        #pragma unroll
        for (int j = 0; j < 4; ++j)
            acc[i][j] = f32x4{0.f, 0.f, 0.f, 0.f};

    stage(0, 0);
    stage(1, 1);
    asm volatile("s_waitcnt vmcnt(8)" ::: "memory");   // KT0 landed
    __builtin_amdgcn_s_barrier();

    // loop-carried G1 frags (a0 k0-half, b0 k0-half), prologue-issued for KT0
    bf16x8 a0[4], b0[4];
    {
        const __bf16* Al = &lds[0][0][0];
        const __bf16* Bl = &lds[0][1][0];
        #pragma unroll
        for (int mi = 0; mi < 4; ++mi)
            a0[mi] = *(const bf16x8*)(Al + (wm * 128 + mi * 16 + fr) * 64 + ((g2) ^ x7) * 8);
        #pragma unroll
        for (int ni = 0; ni < 4; ++ni)
            b0[ni] = *(const bf16x8*)(Bl + (wn * 64 + ni * 16 + fr) * 64 + ((g2) ^ x7) * 8);
    }

    #pragma unroll 1
    for (int i = 0; i < 16; ++i) {
        const int s = i & 1;
        const __bf16* Al = &lds[s][0][0];
        const __bf16* Bl = &lds[s][1][0];

        bf16x8 a0h[4], a1[4], a1h[4], b1[4];

        // issue G2 (a0h k1, b1 k1); then M1 consumes G1 (compiler waits only G1)
        #pragma unroll
        for (int mi = 0; mi < 4; ++mi)
            a0h[mi] = *(const bf16x8*)(Al + (wm * 128 + mi * 16 + fr) * 64 + ((4 + g2) ^ x7) * 8);
        #pragma unroll
        for (int ni = 0; ni < 4; ++ni)
            b1[ni] = *(const bf16x8*)(Bl + (wn * 64 + ni * 16 + fr) * 64 + ((4 + g2) ^ x7) * 8);

        __builtin_amdgcn_s_setprio(1);
        #pragma unroll
        for (int mi = 0; mi < 4; ++mi)
            #pragma unroll
            for (int ni = 0; ni < 4; ++ni)
                acc[mi][ni] = __builtin_amdgcn_mfma_f32_16x16x32_bf16(b0[ni], a0[mi], acc[mi][ni], 0, 0, 0);
        __builtin_amdgcn_s_setprio(0);

        // issue G3 (a1 k0, a1h k1); then M2 consumes G2
        #pragma unroll
        for (int mi = 0; mi < 4; ++mi) {
            const int row = wm * 128 + (mi + 4) * 16 + fr;
            a1[mi]  = *(const bf16x8*)(Al + row * 64 + ((g2    ) ^ x7) * 8);
            a1h[mi] = *(const bf16x8*)(Al + row * 64 + ((4 + g2) ^ x7) * 8);
        }
        __builtin_amdgcn_s_setprio(1);
        #pragma unroll
        for (int mi = 0; mi < 4; ++mi)
            #pragma unroll
            for (int ni = 0; ni < 4; ++ni)
                acc[mi][ni] = __builtin_amdgcn_mfma_f32_16x16x32_bf16(b1[ni], a0h[mi], acc[mi][ni], 0, 0, 0);
        __builtin_amdgcn_s_setprio(0);

        // all reads of slot s drained in every wave -> safe to overwrite
        asm volatile("s_waitcnt lgkmcnt(0)" ::: "memory");
        __builtin_amdgcn_s_barrier();
        if (i < 14) stage(i + 2, s);

        // M3 consumes G3 k0 (registers already in flight/landed)
        __builtin_amdgcn_s_setprio(1);
        #pragma unroll
        for (int mi = 0; mi < 4; ++mi)
            #pragma unroll
            for (int ni = 0; ni < 4; ++ni)
                acc[mi + 4][ni] = __builtin_amdgcn_mfma_f32_16x16x32_bf16(b0[ni], a1[mi], acc[mi + 4][ni], 0, 0, 0);
        __builtin_amdgcn_s_setprio(0);

        // KT i+1 fully landed in all waves, then prefetch next G1 under M4
        if (i < 14) { asm volatile("s_waitcnt vmcnt(8)" ::: "memory"); }
        else        { asm volatile("s_waitcnt vmcnt(0)" ::: "memory"); }
        __builtin_amdgcn_s_barrier();
        if (i < 15) {
            const __bf16* Aln = &lds[s ^ 1][0][0];
            const __bf16* Bln = &lds[s ^ 1][1][0];
            #pragma unroll
            for (int mi = 0; mi < 4; ++mi)
                a0[mi] = *(const bf16x8*)(Aln + (wm * 128 + mi * 16 + fr) * 64 + ((g2) ^ x7) * 8);
            #pragma unroll
            for (int ni = 0; ni < 4; ++ni)
                b0[ni] = *(const bf16x8*)(Bln + (wn * 64 + ni * 16 + fr) * 64 + ((g2) ^ x7) * 8);
        }

        __builtin_amdgcn_s_setprio(1);
        #pragma unroll
        for (int mi = 0; mi < 4; ++mi)
            #pragma unroll
            for (int ni = 0; ni < 4; ++ni)
                acc[mi + 4][ni] = __builtin_amdgcn_mfma_f32_16x16x32_bf16(b1[ni], a1h[mi], acc[mi + 4][ni], 0, 0, 0);
        __builtin_amdgcn_s_setprio(0);
    }

    // ------------------ epilogue ------------------
    // Transposed D: element (row = wm*128+mi*16+fr, col = wn*64+ni*16+g4*4+j).
    // One bf16x4 store per (mi,ni). Lane-local mean partial over b = fr+16*(mi&1).
    const int g4 = lane >> 4;
    const long colb = col0 + wn * 64 + g4 * 4;

    float4 bias4[4];
    #pragma unroll
    for (int ni = 0; ni < 4; ++ni)
        bias4[ni] = *(const float4*)(bias + colb + ni * 16);

    f32x4 msum[2][4];
    #pragma unroll
    for (int bh = 0; bh < 2; ++bh)
        #pragma unroll
        for (int ni = 0; ni < 4; ++ni)
            msum[bh][ni] = f32x4{0.f, 0.f, 0.f, 0.f};

    #pragma unroll
    for (int mi = 0; mi < 8; ++mi) {
        const long row = row0 + wm * 128 + mi * 16 + fr;
        #pragma unroll
        for (int ni = 0; ni < 4; ++ni) {
            f32x4 xv;
            xv[0] = acc[mi][ni][0] + bias4[ni].x;
            xv[1] = acc[mi][ni][1] + bias4[ni].y;
            xv[2] = acc[mi][ni][2] + bias4[ni].z;
            xv[3] = acc[mi][ni][3] + bias4[ni].w;
            bf16x4 xb;
            xb[0] = (__bf16)xv[0]; xb[1] = (__bf16)xv[1];
            xb[2] = (__bf16)xv[2]; xb[3] = (__bf16)xv[3];
            *(bf16x4*)(X + row * 1024 + colb + ni * 16) = xb;
            msum[mi & 1][ni] += xv;
        }
    }

    // cross-wave (wm) reduce of mean partials through LDS (free after K-loop)
    float* ldsf = (float*)&lds[0][0][0];    // 32 b x 256 n f32 = 32 KB
    __syncthreads();                        // all K-loop LDS traffic done
    if (wm == 1) {
        #pragma unroll
        for (int bh = 0; bh < 2; ++bh)
            #pragma unroll
            for (int ni = 0; ni < 4; ++ni)
                *(f32x4*)(ldsf + (bh * 16 + fr) * 256 + wn * 64 + ni * 16 + g4 * 4) = msum[bh][ni];
    }
    __syncthreads();
    if (wm == 0) {
        #pragma unroll
        for (int bh = 0; bh < 2; ++bh) {
            const int b = bh * 16 + fr;
            #pragma unroll
            for (int ni = 0; ni < 4; ++ni) {
                f32x4 other = *(const f32x4*)(ldsf + b * 256 + wn * 64 + ni * 16 + g4 * 4);
                f32x4 tot = msum[bh][ni] + other;
                *(f32x4*)(mpart + ((long)bm * 32 + b) * 1024 + colb + ni * 16) = tot;
            }
        }
    }
}

// ---------------------------------------------------------------------------
// K3: finalize mean from fused partials, gate2[b,h,q] = tanh(m.Wm[q]+bWm[q]).
// ---------------------------------------------------------------------------
__global__ __launch_bounds__(256)
void gate2_k(const float* __restrict__ mpart, const float* __restrict__ Wm,
             const float* __restrict__ bWm, float* __restrict__ g2)
{
    __shared__ float mrow[1024];
    const int b = blockIdx.x;
    const int j4 = threadIdx.x * 4;
    f32x4 s = f32x4{0.f, 0.f, 0.f, 0.f};
    for (int bm = 0; bm < 256; ++bm)
        s += *(const f32x4*)(mpart + ((long)bm * 32 + b) * 1024 + j4);
    mrow[j4 + 0] = s[0] * (1.0f / 2048.0f);
    mrow[j4 + 1] = s[1] * (1.0f / 2048.0f);
    mrow[j4 + 2] = s[2] * (1.0f / 2048.0f);
    mrow[j4 + 3] = s[3] * (1.0f / 2048.0f);
    __syncthreads();
    if (threadIdx.x < 128) {
        const int h = threadIdx.x >> 4;
        const int q = threadIdx.x & 15;
        float d = bWm[q];
        #pragma unroll 8
        for (int k = 0; k < 128; ++k) d += mrow[h * 128 + k] * Wm[q * 128 + k];
        g2[(b * 8 + h) * 16 + q] = tanhf(d);
    }
}

// ---------------------------------------------------------------------------
// K4: scores. X viewed as (524288 rows = bt*8+h, 128). One wave = 16 rows.
// ---------------------------------------------------------------------------
__global__ __launch_bounds__(256)
void scores_k(const __bf16* __restrict__ X, const float* __restrict__ W,
              const float* __restrict__ bW, const float* __restrict__ g2,
              const float* __restrict__ Wh, const float* __restrict__ bWh,
              float* __restrict__ sbuf)
{
    const int tid   = threadIdx.x;
    const int lane  = tid & 63;
    const int w     = tid >> 6;
    const int gw    = blockIdx.x * 4 + w;
    const int rbase = gw * 16;
    const int q     = lane & 15;
    const int g4    = lane >> 4;

    bf16x8 bfr[4];
    #pragma unroll
    for (int c = 0; c < 4; ++c) {
        const float* wp = W + q * 128 + c * 32 + g4 * 8;
        float4 w0 = *(const float4*)wp;
        float4 w1 = *(const float4*)(wp + 4);
        bfr[c] = cvt8(w0, w1);
    }
    const __bf16* xp = X + (long)(rbase + q) * 128 + g4 * 8;
    bf16x8 afr[4];
    #pragma unroll
    for (int c = 0; c < 4; ++c) afr[c] = *(const bf16x8*)(xp + c * 32);

    f32x4 acc = f32x4{0.f, 0.f, 0.f, 0.f};
    #pragma unroll
    for (int c = 0; c < 4; ++c)
        acc = __builtin_amdgcn_mfma_f32_16x16x32_bf16(afr[c], bfr[c], acc, 0, 0, 0);

    const float whq  = Wh[q];
    const float bWv  = bW[q];
    const float bWhv = *bWh;
    #pragma unroll
    for (int r = 0; r < 4; ++r) {
        const int row = rbase + g4 * 4 + r;
        const int h   = row & 7;
        const int bt  = row >> 3;
        const int b   = bt & 31;
        const int t   = bt >> 5;
        float val = tanhf(acc[r] + bWv) * g2[(b * 8 + h) * 16 + q] * whq;
        val += __shfl_xor(val, 1);
        val += __shfl_xor(val, 2);
        val += __shfl_xor(val, 4);
        val += __shfl_xor(val, 8);
        if (q == 0) sbuf[(b * 8 + h) * 2048 + t] = val + bWhv;
    }
}

// ---------------------------------------------------------------------------
// K5: softmax over t, in place. 256 blocks (b*8+h).
// ---------------------------------------------------------------------------
__global__ __launch_bounds__(256)
void softmax_k(float* __restrict__ s)
{
    __shared__ float red[256];
    const int bh = blockIdx.x;
    const int tid = threadIdx.x;
    float* row = s + bh * 2048;
    float4 v0 = *(const float4*)(row + tid * 8);
    float4 v1 = *(const float4*)(row + tid * 8 + 4);
    float v[8] = {v0.x, v0.y, v0.z, v0.w, v1.x, v1.y, v1.z, v1.w};
    float mx = v[0];
    #pragma unroll
    for (int i = 1; i < 8; ++i) mx = fmaxf(mx, v[i]);
    red[tid] = mx;
    __syncthreads();
    for (int st = 128; st > 0; st >>= 1) {
        if (tid < st) red[tid] = fmaxf(red[tid], red[tid + st]);
        __syncthreads();
    }
    mx = red[0];
    __syncthreads();
    float sum = 0.f;
    #pragma unroll
    for (int i = 0; i < 8; ++i) { v[i] = expf(v[i] - mx); sum += v[i]; }
    red[tid] = sum;
    __syncthreads();
    for (int st = 128; st > 0; st >>= 1) {
        if (tid < st) red[tid] += red[tid + st];
        __syncthreads();
    }
    const float inv = 1.0f / red[0];
    *(float4*)(row + tid * 8)     = make_float4(v[0] * inv, v[1] * inv, v[2] * inv, v[3] * inv);
    *(float4*)(row + tid * 8 + 4) = make_float4(v[4] * inv, v[5] * inv, v[6] * inv, v[7] * inv);
}

// ---------------------------------------------------------------------------
// K6: weighted sum over t, t split 8 ways. 2048 blocks.
// ---------------------------------------------------------------------------
__global__ __launch_bounds__(256)
void wsum_k(const float* __restrict__ a, const __bf16* __restrict__ X,
            float* __restrict__ wpart)
{
    __shared__ float pk[8 * 128];
    const int bx = blockIdx.x;
    const int tc = bx & 7;
    const int bh = bx >> 3;
    const int b  = bh >> 3;
    const int h  = bh & 7;
    const int tid = threadIdx.x;
    const int kq = tid & 31;
    const int tr = tid >> 5;
    const float* ar = a + bh * 2048 + tc * 256;
    float a0 = 0.f, a1 = 0.f, a2 = 0.f, a3 = 0.f;
    #pragma unroll 4
    for (int i = tr; i < 256; i += 8) {
        const int t = tc * 256 + i;
        const float av = ar[i];
        bf16x4 xv = *(const bf16x4*)(X + (long)(t * 32 + b) * 1024 + h * 128 + kq * 4);
        a0 += av * (float)xv[0];
        a1 += av * (float)xv[1];
        a2 += av * (float)xv[2];
        a3 += av * (float)xv[3];
    }
    pk[tr * 128 + kq * 4 + 0] = a0;
    pk[tr * 128 + kq * 4 + 1] = a1;
    pk[tr * 128 + kq * 4 + 2] = a2;
    pk[tr * 128 + kq * 4 + 3] = a3;
    __syncthreads();
    if (tid < 128) {
        float s2 = 0.f;
        #pragma unroll
        for (int r = 0; r < 8; ++r) s2 += pk[r * 128 + tid];
        wpart[(long)bx * 128 + tid] = s2;
    }
}

// K7: reduce the 8 t-chunks.
__global__ __launch_bounds__(256)
void wsum_fin(const float* __restrict__ wpart, float* __restrict__ out)
{
    const int idx = blockIdx.x * 256 + threadIdx.x;
    const int k  = idx & 127;
    const int bh = idx >> 7;
    const int b  = bh >> 3;
    const int h  = bh & 7;
    float s = 0.f;
    #pragma unroll
    for (int tc = 0; tc < 8; ++tc) s += wpart[(bh * 8 + tc) * 128 + k];
    out[b * 1024 + h * 128 + k] = s;
}

extern "C" void kernel_launch(void* const* d_in, const int* in_sizes, int n_in,
                              void* d_out, int out_size, void* d_ws, size_t ws_size,
                              hipStream_t stream)
{
    const float* hyp = (const float*)d_in[0];
    const float* Wmh = (const float*)d_in[1];
    const float* bmh = (const float*)d_in[2];
    const float* W   = (const float*)d_in[3];
    const float* bW  = (const float*)d_in[4];
    const float* Wm  = (const float*)d_in[5];
    const float* bWm = (const float*)d_in[6];
    const float* Wh  = (const float*)d_in[7];
    const float* bWh = (const float*)d_in[8];
    float* out = (float*)d_out;

    char* ws = (char*)d_ws;
    const size_t SZ_X   = 134217728;   // X bf16 (65536 x 1024)
    const size_t SZ_AB  = 134217728;   // Ab bf16 hyp
    const size_t SZ_BB  = 2097152;     // Bb bf16 Wmh
    const size_t SZ_MP  = 33554432;    // mpart f32 (256 x 32 x 1024)
    const size_t SZ_G2  = 16384;
    const size_t SZ_SB  = 2097152;

    size_t off = 0;
    __bf16* X     = (__bf16*)(ws + off); off += SZ_X;
    __bf16* Ab    = (__bf16*)(ws + off); off += SZ_AB;
    __bf16* Bb    = (__bf16*)(ws + off); off += SZ_BB;
    float*  mpart = (float*) (ws + off); off += SZ_MP;
    float*  g2    = (float*) (ws + off); off += SZ_G2;
    float*  sbuf  = (float*) (ws + off); off += SZ_SB;
    float*  wpart = (float*) (ws + off);

    cvt_f32_bf16<<<32768, 256, 0, stream>>>(hyp, Ab);
    cvt_f32_bf16<<<512,   256, 0, stream>>>(Wmh, Bb);
    gemm_x_8ph<<<1024, 512, 0, stream>>>(Ab, Bb, bmh, X, mpart);
    gate2_k<<<32, 256, 0, stream>>>(mpart, Wm, bWm, g2);
    scores_k<<<8192, 256, 0, stream>>>(X, W, bW, g2, Wh, bWh, sbuf);
    softmax_k<<<256, 256, 0, stream>>>(sbuf);
    wsum_k<<<2048, 256, 0, stream>>>(sbuf, X, wpart);
    wsum_fin<<<128, 256, 0, stream>>>(wpart, out);
}